// Round 2
// baseline (28916.913 us; speedup 1.0000x reference)
//
#include <hip/hip_runtime.h>
#include <hip/hip_bf16.h>
#include <math.h>

// Problem dims
#define SLEN 256
#define BSZ  128
#define DIN  128
#define HSZ  512
#define HH2  1024
#define GG3  1536
#define OSZ  25

typedef _Float16 h8 __attribute__((ext_vector_type(8)));
typedef float    f4 __attribute__((ext_vector_type(4)));

// Persistent-kernel geometry
#define NBLK 128
#define NTHR 512
#define NWAV ((NBLK * NTHR) / 64)  // 1024 waves

struct P_t {
  // fp32 inputs used directly
  const float *x, *noise, *b_cin, *b1, *b2, *b3, *w4, *b4, *b_ih, *b_hh, *w_out, *b_out;
  // f16 transposed weights [N,K]
  _Float16 *WT1, *WT2, *WT3, *WTih, *WThh, *WTcin;
  // f16 buffers
  _Float16 *CIN, *COM, *Z1, *Z2, *HF16;
  // fp32 buffers
  float *LOGI, *Z3, *GX, *GH, *HGRU, *HF32, *CF32, *NF32, *HFIN;
  unsigned *CTR;
  float *out;  // fp32 output (reference output dtype is float32)
};

// ---------------- barrier helpers (device-scope split barrier) ----------------
__device__ __forceinline__ void blk_arrive(unsigned* c) {
  __syncthreads();
  if (threadIdx.x == 0) { __threadfence(); atomicAdd(c, 1u); }
}
__device__ __forceinline__ void blk_wait(unsigned* c, unsigned target) {
  if (threadIdx.x == 0) {
    while (__hip_atomic_load(c, __ATOMIC_RELAXED, __HIP_MEMORY_SCOPE_AGENT) < target)
      __builtin_amdgcn_s_sleep(2);
    __threadfence();
  }
  __syncthreads();
}

// ---------------- 16x16 MFMA tile, full-K, f16 inputs, fp32 accum ----------------
// A: [M,K] f16 row-major (lda), BT: [N,K] f16 row-major. Out = act(A@B + bias).
template<int K, bool RELU, bool F16OUT>
__device__ __forceinline__ void tile16(const _Float16* __restrict__ A, int lda,
    const _Float16* __restrict__ BT, const float* __restrict__ bias,
    void* __restrict__ Out, int ldo, int m0, int n0, int lane) {
  const int ml = lane & 15, q = lane >> 4;
  const _Float16* ap = A + (size_t)(m0 + ml) * lda + q * 8;
  const _Float16* bp = BT + (size_t)(n0 + ml) * K + q * 8;
  f4 acc = {0.f, 0.f, 0.f, 0.f};
#pragma unroll 16
  for (int k = 0; k < K; k += 32)
    acc = __builtin_amdgcn_mfma_f32_16x16x32_f16(*(const h8*)(ap + k),
                                                 *(const h8*)(bp + k), acc, 0, 0, 0);
  const int col = n0 + ml;
  const float bia = bias[col];
#pragma unroll
  for (int r = 0; r < 4; ++r) {
    const int row = m0 + q * 4 + r;
    float v = acc[r] + bia;
    if (RELU) v = fmaxf(v, 0.f);
    if (F16OUT) ((_Float16*)Out)[(size_t)row * ldo + col] = (_Float16)v;
    else        ((float*)Out)[(size_t)row * ldo + col]    = v;
  }
}

// ---------------- setup kernels ----------------
// fp32 [K,N] -> f16 [N,K]
__global__ __launch_bounds__(256) void transpose_cvt(const float* __restrict__ src,
    _Float16* __restrict__ dst, int K, int N) {
  __shared__ float tl[32][33];
  int nt = N >> 5;
  int bx = blockIdx.x % nt, by = blockIdx.x / nt;
  int n0 = bx << 5, k0 = by << 5;
  int tx = threadIdx.x & 31, ty = threadIdx.x >> 5;
#pragma unroll
  for (int i = 0; i < 4; ++i) {
    int r = ty + (i << 3);
    tl[r][tx] = src[(size_t)(k0 + r) * N + n0 + tx];
  }
  __syncthreads();
#pragma unroll
  for (int i = 0; i < 4; ++i) {
    int r = ty + (i << 3);
    dst[(size_t)(n0 + r) * K + k0 + tx] = (_Float16)tl[tx][r];
  }
}

// c_in[t,b,:] = tanh(x[b,t,:] @ w_cin + b_cin) as f16; also logistic noise.
__global__ __launch_bounds__(256) void cin_kernel(P_t P) {
  int tid = blockIdx.x * blockDim.x + threadIdx.x;
  if (tid < SLEN * BSZ) {
    float u = P.noise[tid];
    P.LOGI[tid] = logf(u) - log1pf(-u);
  }
  int gw = tid >> 6, lane = tid & 63;
  int nw = (gridDim.x * blockDim.x) >> 6;
  int ml = lane & 15, q = lane >> 4;
  const int MT = (SLEN * BSZ) / 16;  // 2048 row-tiles, 8 col-tiles of 64
  for (int tt = gw; tt < MT * 8; tt += nw) {
    int mt = tt & (MT - 1), nt = tt / MT;
    int m0 = mt * 16, n0 = nt * 64;
    int m = m0 + ml, b = m & 127, s = m >> 7;
    const float* ap = P.x + ((size_t)b * SLEN + s) * DIN + q * 8;
    const _Float16* bp = P.WTcin + (size_t)(n0 + ml) * DIN + q * 8;
    f4 a0 = {0,0,0,0}, a1 = a0, a2 = a0, a3 = a0;
#pragma unroll
    for (int k = 0; k < DIN; k += 32) {
      f4 lo = *(const f4*)(ap + k);
      f4 hi = *(const f4*)(ap + k + 4);
      h8 av;
      av[0] = (_Float16)lo[0]; av[1] = (_Float16)lo[1];
      av[2] = (_Float16)lo[2]; av[3] = (_Float16)lo[3];
      av[4] = (_Float16)hi[0]; av[5] = (_Float16)hi[1];
      av[6] = (_Float16)hi[2]; av[7] = (_Float16)hi[3];
      a0 = __builtin_amdgcn_mfma_f32_16x16x32_f16(av, *(const h8*)(bp + k),            a0, 0,0,0);
      a1 = __builtin_amdgcn_mfma_f32_16x16x32_f16(av, *(const h8*)(bp + 16*DIN + k),   a1, 0,0,0);
      a2 = __builtin_amdgcn_mfma_f32_16x16x32_f16(av, *(const h8*)(bp + 32*DIN + k),   a2, 0,0,0);
      a3 = __builtin_amdgcn_mfma_f32_16x16x32_f16(av, *(const h8*)(bp + 48*DIN + k),   a3, 0,0,0);
    }
#pragma unroll
    for (int r = 0; r < 4; ++r) {
      int row = m0 + q * 4 + r;
      int c0 = n0 + ml;
      P.CIN[(size_t)row * HSZ + c0     ] = (_Float16)tanhf(a0[r] + P.b_cin[c0]);
      P.CIN[(size_t)row * HSZ + c0 + 16] = (_Float16)tanhf(a1[r] + P.b_cin[c0 + 16]);
      P.CIN[(size_t)row * HSZ + c0 + 32] = (_Float16)tanhf(a2[r] + P.b_cin[c0 + 32]);
      P.CIN[(size_t)row * HSZ + c0 + 48] = (_Float16)tanhf(a3[r] + P.b_cin[c0 + 48]);
    }
  }
}

// zero state, seed com = [c0=0, c_in[0]], zero counters
__global__ __launch_bounds__(256) void init_kernel(P_t P) {
  int idx = blockIdx.x * 256 + threadIdx.x;
  if (idx < BSZ * HSZ) {
    int row = idx >> 9, i = idx & 511;
    P.CF32[idx] = 0.f; P.HF32[idx] = 0.f; P.HF16[idx] = (_Float16)0.f;
    P.COM[(size_t)row * HH2 + i] = (_Float16)0.f;
    P.COM[(size_t)row * HH2 + 512 + i] = P.CIN[idx];
  }
  if (idx < BSZ) P.NF32[idx] = 0.f;
  if (idx < 128) P.CTR[idx] = 0u;
}

// ---------------- main persistent scan kernel ----------------
__global__ __launch_bounds__(NTHR, 2) void rnn_main(P_t P) {
  const int tid = threadIdx.x;
  const int lane = tid & 63;
  const int gwave = ((blockIdx.x * NTHR) + tid) >> 6;
  // spread tasks one-per-block first so all CUs engage
  const int tt0 = (gwave & 7) * NBLK + (gwave >> 3);
  const int gtid = blockIdx.x * NTHR + tid;
  const unsigned NB = NBLK;
  unsigned* CT = P.CTR;
#define CTRP(ph, g) (CT + ((ph) * 2 + (g)) * 16)

  for (int t = 0; t < SLEN; ++t) {
    // ---- phase 1: z1 = relu(com@W1+b1); gx = c@Wih+bih ----
    for (int g = 0; g < 2; ++g) {
      blk_wait(CTRP(3, g), NB * (unsigned)t);
      const _Float16* Ac = P.COM + (size_t)g * 64 * HH2;
      for (int tt = tt0; tt < 640; tt += NWAV) {
        if (tt < 256)
          tile16<1024, true, true>(Ac, HH2, P.WT1, P.b1, P.Z1 + (size_t)g * 64 * HH2, HH2,
                                   (tt & 3) << 4, (tt >> 2) << 4, lane);
        else {
          int u = tt - 256;
          tile16<512, false, false>(Ac, HH2, P.WTih, P.b_ih, P.GX + (size_t)g * 64 * GG3, GG3,
                                    (u & 3) << 4, (u >> 2) << 4, lane);
        }
      }
      blk_arrive(CTRP(0, g));
    }
    // ---- phase 2: z2 = relu(z1@W2+b2); gh = h@Whh+bhh ----
    for (int g = 0; g < 2; ++g) {
      blk_wait(CTRP(0, g), NB * (unsigned)(t + 1));
      for (int tt = tt0; tt < 640; tt += NWAV) {
        if (tt < 256)
          tile16<1024, true, true>(P.Z1 + (size_t)g * 64 * HH2, HH2, P.WT2, P.b2,
                                   P.Z2 + (size_t)g * 64 * HH2, HH2,
                                   (tt & 3) << 4, (tt >> 2) << 4, lane);
        else {
          int u = tt - 256;
          tile16<512, false, false>(P.HF16 + (size_t)g * 64 * HSZ, HSZ, P.WThh, P.b_hh,
                                    P.GH + (size_t)g * 64 * GG3, GG3,
                                    (u & 3) << 4, (u >> 2) << 4, lane);
        }
      }
      blk_arrive(CTRP(1, g));
    }
    // ---- phase 3: z3 = relu(z2@W3+b3) (fp32); GRU gate -> hgru ----
    for (int g = 0; g < 2; ++g) {
      blk_wait(CTRP(1, g), NB * (unsigned)(t + 1));
      for (int tt = tt0; tt < 256; tt += NWAV)
        tile16<1024, true, false>(P.Z2 + (size_t)g * 64 * HH2, HH2, P.WT3, P.b3,
                                  P.Z3 + (size_t)g * 64 * HH2, HH2,
                                  (tt & 3) << 4, (tt >> 2) << 4, lane);
      for (int i = gtid; i < 64 * HSZ; i += NBLK * NTHR) {
        int row = (g * 64) + (i >> 9), ci = i & 511;
        float xr = P.GX[(size_t)row * GG3 + ci];
        float xz = P.GX[(size_t)row * GG3 + 512 + ci];
        float xn = P.GX[(size_t)row * GG3 + 1024 + ci];
        float hr = P.GH[(size_t)row * GG3 + ci];
        float hz = P.GH[(size_t)row * GG3 + 512 + ci];
        float hn = P.GH[(size_t)row * GG3 + 1024 + ci];
        float rr = 1.f / (1.f + expf(-(xr + hr)));
        float zz = 1.f / (1.f + expf(-(xz + hz)));
        float nn = tanhf(xn + rr * hn);
        float hv = P.HF32[(size_t)row * HSZ + ci];
        P.HGRU[(size_t)row * HSZ + ci] = (1.f - zz) * nn + zz * hv;
      }
      blk_arrive(CTRP(2, g));
    }
    // ---- phase 4: combine (logit dot, alpha, state update, next com) ----
    for (int g = 0; g < 2; ++g) {
      blk_wait(CTRP(2, g), NB * (unsigned)(t + 1));
      if ((gwave & 7) == 0 && (gwave >> 3) < 64) {
        const int row = g * 64 + (gwave >> 3);
        float a = 0.f;
#pragma unroll
        for (int j = 0; j < 16; ++j) {
          int i2 = lane + (j << 6);
          a += P.Z3[(size_t)row * HH2 + i2] * P.w4[i2];
        }
#pragma unroll
        for (int off = 32; off > 0; off >>= 1) a += __shfl_xor(a, off);
        float lg = (a + P.b4[0] + P.LOGI[t * BSZ + row]) / 0.1f;
        float alpha = 1.f / (1.f + expf(-lg));
        float om = 1.f - alpha;
        float np = P.NF32[row];
        float nnew = np * om + 1.f;
#pragma unroll
        for (int j = 0; j < 8; ++j) {
          int i2 = lane + (j << 6);
          size_t hi = (size_t)row * HSZ + i2;
          float hv = P.HF32[hi], hg = P.HGRU[hi];
          float hnew = hv * om + alpha * hg;
          P.HF32[hi] = hnew;
          P.HF16[hi] = (_Float16)hnew;
          float cv = P.CF32[hi];
          float ci = (float)P.CIN[((size_t)t * BSZ + row) * HSZ + i2];
          float cnew = (cv * np * om + ci) / nnew;
          P.CF32[hi] = cnew;
          P.COM[(size_t)row * HH2 + i2] = (_Float16)cnew;
          if (t + 1 < SLEN)
            P.COM[(size_t)row * HH2 + 512 + i2] = P.CIN[((size_t)(t + 1) * BSZ + row) * HSZ + i2];
        }
        if (lane == 0) P.NF32[row] = nnew;
      }
      blk_arrive(CTRP(3, g));
    }
  }

  // ---- tail: final GRU step + output GEMM (fp32) ----
  for (int g = 0; g < 2; ++g) {
    blk_wait(CTRP(3, g), NB * (unsigned)SLEN);
    const _Float16* Ac = P.COM + (size_t)g * 64 * HH2;
    for (int tt = tt0; tt < 768; tt += NWAV) {
      if (tt < 384)
        tile16<512, false, false>(Ac, HH2, P.WTih, P.b_ih, P.GX + (size_t)g * 64 * GG3, GG3,
                                  (tt & 3) << 4, (tt >> 2) << 4, lane);
      else {
        int u = tt - 384;
        tile16<512, false, false>(P.HF16 + (size_t)g * 64 * HSZ, HSZ, P.WThh, P.b_hh,
                                  P.GH + (size_t)g * 64 * GG3, GG3,
                                  (u & 3) << 4, (u >> 2) << 4, lane);
      }
    }
    blk_arrive(CTRP(0, g));
  }
  for (int g = 0; g < 2; ++g) {
    blk_wait(CTRP(0, g), NB * (unsigned)(SLEN + 1));
    for (int i = gtid; i < 64 * HSZ; i += NBLK * NTHR) {
      int row = (g * 64) + (i >> 9), ci = i & 511;
      float xr = P.GX[(size_t)row * GG3 + ci];
      float xz = P.GX[(size_t)row * GG3 + 512 + ci];
      float xn = P.GX[(size_t)row * GG3 + 1024 + ci];
      float hr = P.GH[(size_t)row * GG3 + ci];
      float hz = P.GH[(size_t)row * GG3 + 512 + ci];
      float hn = P.GH[(size_t)row * GG3 + 1024 + ci];
      float rr = 1.f / (1.f + expf(-(xr + hr)));
      float zz = 1.f / (1.f + expf(-(xz + hz)));
      float nn = tanhf(xn + rr * hn);
      float hv = P.HF32[(size_t)row * HSZ + ci];
      P.HFIN[(size_t)row * HSZ + ci] = (1.f - zz) * nn + zz * hv;
    }
    blk_arrive(CTRP(1, g));
  }
  blk_wait(CTRP(1, 0), NB * (unsigned)(SLEN + 1));
  blk_wait(CTRP(1, 1), NB * (unsigned)(SLEN + 1));
  if ((gwave & 7) == 0) {
    const int row = gwave >> 3;  // 0..127, one wave (wave 0) per block
    if (row < BSZ) {
      float accs[OSZ];
#pragma unroll
      for (int c = 0; c < OSZ; ++c) accs[c] = 0.f;
#pragma unroll
      for (int j = 0; j < 8; ++j) {
        float hv = P.HFIN[(size_t)row * HSZ + lane * 8 + j];
        const float* wr = P.w_out + (size_t)(lane * 8 + j) * OSZ;
#pragma unroll
        for (int c = 0; c < OSZ; ++c) accs[c] += hv * wr[c];
      }
#pragma unroll
      for (int c = 0; c < OSZ; ++c) {
        float v = accs[c];
#pragma unroll
        for (int off = 32; off > 0; off >>= 1) v += __shfl_xor(v, off);
        if (lane == 0) P.out[row * OSZ + c] = v + P.b_out[c];
      }
    }
  }
}

// ---------------- host ----------------
extern "C" void kernel_launch(void* const* d_in, const int* in_sizes, int n_in,
                              void* d_out, int out_size, void* d_ws, size_t ws_size,
                              hipStream_t stream) {
  const float* x     = (const float*)d_in[0];
  const float* noise = (const float*)d_in[1];
  const float* w_cin = (const float*)d_in[2];
  const float* b_cin = (const float*)d_in[3];
  const float* w1    = (const float*)d_in[4];
  const float* b1    = (const float*)d_in[5];
  const float* w2    = (const float*)d_in[6];
  const float* b2    = (const float*)d_in[7];
  const float* w3    = (const float*)d_in[8];
  const float* b3    = (const float*)d_in[9];
  const float* w4    = (const float*)d_in[10];
  const float* b4    = (const float*)d_in[11];
  const float* w_ih  = (const float*)d_in[12];
  const float* b_ih  = (const float*)d_in[13];
  const float* w_hh  = (const float*)d_in[14];
  const float* b_hh  = (const float*)d_in[15];
  const float* w_out = (const float*)d_in[16];
  const float* b_out = (const float*)d_in[17];

  char* ws = (char*)d_ws;
  size_t off = 0;
  auto alloc = [&](size_t bytes) -> void* {
    void* p = ws + off;
    off = (off + bytes + 255) & ~(size_t)255;
    return p;
  };

  P_t P;
  P.x = x; P.noise = noise; P.b_cin = b_cin; P.b1 = b1; P.b2 = b2; P.b3 = b3;
  P.w4 = w4; P.b4 = b4; P.b_ih = b_ih; P.b_hh = b_hh; P.w_out = w_out; P.b_out = b_out;
  P.WT1   = (_Float16*)alloc((size_t)HH2 * HH2 * 2);
  P.WT2   = (_Float16*)alloc((size_t)HH2 * HH2 * 2);
  P.WT3   = (_Float16*)alloc((size_t)HH2 * HH2 * 2);
  P.WTih  = (_Float16*)alloc((size_t)GG3 * HSZ * 2);
  P.WThh  = (_Float16*)alloc((size_t)GG3 * HSZ * 2);
  P.WTcin = (_Float16*)alloc((size_t)HSZ * DIN * 2);
  P.CIN   = (_Float16*)alloc((size_t)SLEN * BSZ * HSZ * 2);
  P.COM   = (_Float16*)alloc((size_t)BSZ * HH2 * 2);
  P.Z1    = (_Float16*)alloc((size_t)BSZ * HH2 * 2);
  P.Z2    = (_Float16*)alloc((size_t)BSZ * HH2 * 2);
  P.HF16  = (_Float16*)alloc((size_t)BSZ * HSZ * 2);
  P.LOGI  = (float*)alloc((size_t)SLEN * BSZ * 4);
  P.Z3    = (float*)alloc((size_t)BSZ * HH2 * 4);
  P.GX    = (float*)alloc((size_t)BSZ * GG3 * 4);
  P.GH    = (float*)alloc((size_t)BSZ * GG3 * 4);
  P.HGRU  = (float*)alloc((size_t)BSZ * HSZ * 4);
  P.HF32  = (float*)alloc((size_t)BSZ * HSZ * 4);
  P.CF32  = (float*)alloc((size_t)BSZ * HSZ * 4);
  P.NF32  = (float*)alloc((size_t)BSZ * 4);
  P.HFIN  = (float*)alloc((size_t)BSZ * HSZ * 4);
  P.CTR   = (unsigned*)alloc(128 * 4);
  P.out   = (float*)d_out;

  // weight transposes: fp32 [K,N] -> f16 [N,K]
  transpose_cvt<<<(HH2 / 32) * (HH2 / 32), 256, 0, stream>>>(w1, P.WT1, HH2, HH2);
  transpose_cvt<<<(HH2 / 32) * (HH2 / 32), 256, 0, stream>>>(w2, P.WT2, HH2, HH2);
  transpose_cvt<<<(HH2 / 32) * (HH2 / 32), 256, 0, stream>>>(w3, P.WT3, HH2, HH2);
  transpose_cvt<<<(GG3 / 32) * (HSZ / 32), 256, 0, stream>>>(w_ih, P.WTih, HSZ, GG3);
  transpose_cvt<<<(GG3 / 32) * (HSZ / 32), 256, 0, stream>>>(w_hh, P.WThh, HSZ, GG3);
  transpose_cvt<<<(HSZ / 32) * (DIN / 32), 256, 0, stream>>>(w_cin, P.WTcin, DIN, HSZ);

  cin_kernel<<<1024, 256, 0, stream>>>(P);
  init_kernel<<<256, 256, 0, stream>>>(P);
  rnn_main<<<NBLK, NTHR, 0, stream>>>(P);
}

// Round 5
// 14403.334 us; speedup vs baseline: 2.0077x; 2.0077x over previous
//
#include <hip/hip_runtime.h>
#include <math.h>

// Problem dims
#define SLEN 256
#define BSZ  128
#define DIN  128
#define HSZ  512
#define HH2  1024
#define GG3  1536
#define OSZ  25

typedef _Float16 h8 __attribute__((ext_vector_type(8)));
typedef float    f4 __attribute__((ext_vector_type(4)));

// Dataflow-pipeline geometry: 256 blocks x 512 threads, 1 block/CU.
// Roles: b<64: W1 | b<128: W2 | b<192: W3(+PART) | b<256: gates(+P4)
#define NBLK 256
#define NTHR 512

// Static LDS: max(W-tile 16x1032 f16 = 33,024B, 3 gate tiles 3x16x520 f16 = 49,920B)
#define SM_F16 24960  // 49,920 bytes

struct P_t {
  const float *x, *noise, *b_cin, *b1, *b2, *b3, *w4, *b4, *b_ih, *b_hh, *w_out, *b_out;
  _Float16 *WT1, *WT2, *WT3, *WTih, *WThh, *WTcin;  // f16 transposed [N][K]
  _Float16 *CIN, *COM, *Z1, *Z2, *HF16;
  float *LOGI, *GX, *GH, *PART, *HF32, *CF32, *NF32;
  unsigned *CTR;
  float *out;
};

// ---------------- split device barrier (R2-proven) ----------------
__device__ __forceinline__ void blk_arrive(unsigned* c) {
  __syncthreads();
  if (threadIdx.x == 0) { __threadfence(); atomicAdd(c, 1u); }
}
__device__ __forceinline__ void blk_wait(unsigned* c, unsigned target) {
  if (threadIdx.x == 0) {
    while (__hip_atomic_load(c, __ATOMIC_RELAXED, __HIP_MEMORY_SCOPE_AGENT) < target)
      __builtin_amdgcn_s_sleep(2);
    __threadfence();
  }
  __syncthreads();
}

// 16x16 MFMA tile: A [M,K] f16 global row-major, B tile in LDS [16][ldb].
template<int K>
__device__ __forceinline__ f4 gemm_tile(const _Float16* __restrict__ A, int lda,
                                        const _Float16* __restrict__ Bs, int ldb,
                                        int m0, int ml, int q) {
  const _Float16* ap = A + (size_t)(m0 + ml) * lda + q * 8;
  const _Float16* bp = Bs + ml * ldb + q * 8;
  f4 acc = {0.f, 0.f, 0.f, 0.f};
#pragma unroll 16
  for (int k = 0; k < K; k += 32)
    acc = __builtin_amdgcn_mfma_f32_16x16x32_f16(*(const h8*)(ap + k),
                                                 *(const h8*)(bp + k), acc, 0, 0, 0);
  return acc;
}

// ---------------- setup kernels (R2-proven) ----------------
__global__ __launch_bounds__(256) void transpose_cvt(const float* __restrict__ src,
    _Float16* __restrict__ dst, int K, int N) {
  __shared__ float tl[32][33];
  int nt = N >> 5;
  int bx = blockIdx.x % nt, by = blockIdx.x / nt;
  int n0 = bx << 5, k0 = by << 5;
  int tx = threadIdx.x & 31, ty = threadIdx.x >> 5;
#pragma unroll
  for (int i = 0; i < 4; ++i) {
    int r = ty + (i << 3);
    tl[r][tx] = src[(size_t)(k0 + r) * N + n0 + tx];
  }
  __syncthreads();
#pragma unroll
  for (int i = 0; i < 4; ++i) {
    int r = ty + (i << 3);
    dst[(size_t)(n0 + r) * K + k0 + tx] = (_Float16)tl[tx][r];
  }
}

__global__ __launch_bounds__(256) void cin_kernel(P_t P) {
  int tid = blockIdx.x * blockDim.x + threadIdx.x;
  if (tid < SLEN * BSZ) {
    float u = P.noise[tid];
    P.LOGI[tid] = logf(u) - log1pf(-u);
  }
  int gw = tid >> 6, lane = tid & 63;
  int nw = (gridDim.x * blockDim.x) >> 6;
  int ml = lane & 15, q = lane >> 4;
  const int MT = (SLEN * BSZ) / 16;
  for (int tt = gw; tt < MT * 8; tt += nw) {
    int mt = tt & (MT - 1), nt = tt / MT;
    int m0 = mt * 16, n0 = nt * 64;
    int m = m0 + ml, b = m & 127, s = m >> 7;
    const float* ap = P.x + ((size_t)b * SLEN + s) * DIN + q * 8;
    const _Float16* bp = P.WTcin + (size_t)(n0 + ml) * DIN + q * 8;
    f4 a0 = {0,0,0,0}, a1 = a0, a2 = a0, a3 = a0;
#pragma unroll
    for (int k = 0; k < DIN; k += 32) {
      f4 lo = *(const f4*)(ap + k);
      f4 hi = *(const f4*)(ap + k + 4);
      h8 av;
      av[0] = (_Float16)lo[0]; av[1] = (_Float16)lo[1];
      av[2] = (_Float16)lo[2]; av[3] = (_Float16)lo[3];
      av[4] = (_Float16)hi[0]; av[5] = (_Float16)hi[1];
      av[6] = (_Float16)hi[2]; av[7] = (_Float16)hi[3];
      a0 = __builtin_amdgcn_mfma_f32_16x16x32_f16(av, *(const h8*)(bp + k),          a0, 0,0,0);
      a1 = __builtin_amdgcn_mfma_f32_16x16x32_f16(av, *(const h8*)(bp + 16*DIN + k), a1, 0,0,0);
      a2 = __builtin_amdgcn_mfma_f32_16x16x32_f16(av, *(const h8*)(bp + 32*DIN + k), a2, 0,0,0);
      a3 = __builtin_amdgcn_mfma_f32_16x16x32_f16(av, *(const h8*)(bp + 48*DIN + k), a3, 0,0,0);
    }
#pragma unroll
    for (int r = 0; r < 4; ++r) {
      int row = m0 + q * 4 + r;
      int c0 = n0 + ml;
      P.CIN[(size_t)row * HSZ + c0     ] = (_Float16)tanhf(a0[r] + P.b_cin[c0]);
      P.CIN[(size_t)row * HSZ + c0 + 16] = (_Float16)tanhf(a1[r] + P.b_cin[c0 + 16]);
      P.CIN[(size_t)row * HSZ + c0 + 32] = (_Float16)tanhf(a2[r] + P.b_cin[c0 + 32]);
      P.CIN[(size_t)row * HSZ + c0 + 48] = (_Float16)tanhf(a3[r] + P.b_cin[c0 + 48]);
    }
  }
}

__global__ __launch_bounds__(256) void init_kernel(P_t P) {
  int idx = blockIdx.x * 256 + threadIdx.x;
  if (idx < BSZ * HSZ) {
    int row = idx >> 9, i = idx & 511;
    P.CF32[idx] = 0.f; P.HF32[idx] = 0.f; P.HF16[idx] = (_Float16)0.f;
    P.COM[(size_t)row * HH2 + i] = (_Float16)0.f;
    P.COM[(size_t)row * HH2 + 512 + i] = P.CIN[idx];
  }
  if (idx < BSZ) P.NF32[idx] = 0.f;
  if (idx < 512) P.CTR[idx] = 0u;
}

// ---------------- main persistent dataflow kernel ----------------
__global__ __launch_bounds__(NTHR) void rnn_main(P_t P) {
  __shared__ __align__(16) _Float16 sm[SM_F16];
  __shared__ float sred[8];
  const int tid = threadIdx.x;
  const int b = blockIdx.x;
  const int lane = tid & 63;
  const int wv = tid >> 6;           // 0..7
  const int ml = lane & 15, q = lane >> 4;

  unsigned* CTA = P.CTR;             // z1 ready       (64 W1-block arrivals/step)
  unsigned* CTB = P.CTR + 64;        // z2 ready       (64 W2)
  unsigned* CTC = P.CTR + 128;       // PART ready     (64 W3)
  unsigned* CTD = P.CTR + 192;       // gx/gh ready    (64 gate)
  unsigned* CTE = P.CTR + 256;       // state updated  (64 gate)

  // ---- stage this block's weight slice into LDS ----
  if (b < 192) {
    const _Float16* W = (b < 64) ? P.WT1 : (b < 128) ? P.WT2 : P.WT3;
    const int j16 = b & 63;
#pragma unroll
    for (int rep = 0; rep < 2; ++rep) {
      int idx = tid + rep * 512;
      int j = idx >> 6, ck = (idx & 63) * 16;
      *(h8*)(sm + j * 1032 + ck)     = *(const h8*)(W + (size_t)(16 * j16 + j) * HH2 + ck);
      *(h8*)(sm + j * 1032 + ck + 8) = *(const h8*)(W + (size_t)(16 * j16 + j) * HH2 + ck + 8);
    }
  } else {
    const int i = b - 192;
    int j = tid >> 5, c2 = (tid & 31) * 16;
#pragma unroll
    for (int s = 0; s < 3; ++s) {
      int g = 3 * i + s;
      const _Float16* src = (g < 96) ? (P.WTih + (size_t)(16 * g + j) * HSZ)
                                     : (P.WThh + (size_t)(16 * (g - 96) + j) * HSZ);
      // BUGFIX (R3/R4 NaN root cause): each 16-element chunk needs BOTH h8 halves;
      // previously only [c2..c2+7] was staged, leaving [c2+8..c2+15] as
      // uninitialized LDS (arbitrary bits incl. f16 NaN) feeding the gate MFMAs.
      *(h8*)(sm + s * 8320 + j * 520 + c2)     = *(const h8*)(src + c2);
      *(h8*)(sm + s * 8320 + j * 520 + c2 + 8) = *(const h8*)(src + c2 + 8);
    }
  }
  __syncthreads();

  if (b < 64) {
    // ---- W1 role: z1 = relu(com @ W1 + b1), own cols 16b..16b+15 ----
    const int colb = 16 * b + ml;
    const float bia = P.b1[colb];
    for (int t = 0; t < SLEN; ++t) {
      blk_wait(CTE, 64u * (unsigned)t);
      f4 a = gemm_tile<1024>(P.COM, HH2, sm, 1032, wv * 16, ml, q);
#pragma unroll
      for (int r = 0; r < 4; ++r)
        P.Z1[(size_t)(wv * 16 + q * 4 + r) * HH2 + colb] = (_Float16)fmaxf(a[r] + bia, 0.f);
      blk_arrive(CTA);
    }
  } else if (b < 128) {
    // ---- W2 role: z2 = relu(z1 @ W2 + b2) ----
    const int colb = 16 * (b - 64) + ml;
    const float bia = P.b2[colb];
    for (int t = 0; t < SLEN; ++t) {
      blk_wait(CTA, 64u * (unsigned)(t + 1));
      f4 a = gemm_tile<1024>(P.Z1, HH2, sm, 1032, wv * 16, ml, q);
#pragma unroll
      for (int r = 0; r < 4; ++r)
        P.Z2[(size_t)(wv * 16 + q * 4 + r) * HH2 + colb] = (_Float16)fmaxf(a[r] + bia, 0.f);
      blk_arrive(CTB);
    }
  } else if (b < 192) {
    // ---- W3 role: z3 tile, fold w4-dot into PART[k][row] ----
    const int k = b - 128;
    const int colb = 16 * k + ml;
    const float bia = P.b3[colb];
    const float w4v = P.w4[colb];
    for (int t = 0; t < SLEN; ++t) {
      blk_wait(CTB, 64u * (unsigned)(t + 1));
      f4 a = gemm_tile<1024>(P.Z2, HH2, sm, 1032, wv * 16, ml, q);
#pragma unroll
      for (int r = 0; r < 4; ++r) {
        float v = fmaxf(a[r] + bia, 0.f) * w4v;
        v += __shfl_xor(v, 1); v += __shfl_xor(v, 2);
        v += __shfl_xor(v, 4); v += __shfl_xor(v, 8);
        if (ml == 0) P.PART[(size_t)k * BSZ + wv * 16 + q * 4 + r] = v;
      }
      blk_arrive(CTC);
    }
  } else {
    // ---- gate role: gx/gh GEMMs, then alpha + state update for rows 2i,2i+1 ----
    const int i = b - 192;
    for (int t = 0; t < SLEN; ++t) {
      blk_wait(CTE, 64u * (unsigned)t);
#pragma unroll
      for (int s = 0; s < 3; ++s) {
        int g = 3 * i + s;
        bool ih = (g < 96);
        int gl = ih ? g : g - 96;
        int cg = 16 * gl + ml;
        f4 a = ih ? gemm_tile<512>(P.COM, HH2, sm + s * 8320, 520, wv * 16, ml, q)
                  : gemm_tile<512>(P.HF16, HSZ, sm + s * 8320, 520, wv * 16, ml, q);
        float bia = ih ? P.b_ih[cg] : P.b_hh[cg];
        float* dst = ih ? P.GX : P.GH;
#pragma unroll
        for (int r = 0; r < 4; ++r)
          dst[(size_t)(wv * 16 + q * 4 + r) * GG3 + cg] = a[r] + bia;
      }
      blk_arrive(CTD);
      blk_wait(CTC, 64u * (unsigned)(t + 1));
      blk_wait(CTD, 64u * (unsigned)(t + 1));
      // alpha for rows 2i, 2i+1
      if (wv < 2) {
        int row = 2 * i + wv;
        float v = P.PART[(size_t)lane * BSZ + row];
#pragma unroll
        for (int off = 32; off > 0; off >>= 1) v += __shfl_xor(v, off);
        if (lane == 0) {
          float lg = (v + P.b4[0] + P.LOGI[t * BSZ + row]) * 10.0f;
          float alpha = 1.f / (1.f + expf(-lg));
          float om = 1.f - alpha;
          float n_old = P.NF32[row];
          float nnew = n_old * om + 1.f;
          P.NF32[row] = nnew;
          sred[wv * 4 + 0] = alpha; sred[wv * 4 + 1] = om;
          sred[wv * 4 + 2] = n_old * om; sred[wv * 4 + 3] = nnew;
        }
      }
      __syncthreads();
      {
        const int col = tid;  // 0..511
#pragma unroll
        for (int rr = 0; rr < 2; ++rr) {
          int row = 2 * i + rr;
          float alpha = sred[rr * 4], om = sred[rr * 4 + 1];
          float nom = sred[rr * 4 + 2], nnew = sred[rr * 4 + 3];
          size_t go = (size_t)row * GG3 + col;
          float xr = P.GX[go], xz = P.GX[go + 512], xn = P.GX[go + 1024];
          float hr = P.GH[go], hz = P.GH[go + 512], hn = P.GH[go + 1024];
          float rgate = 1.f / (1.f + expf(-(xr + hr)));
          float zgate = 1.f / (1.f + expf(-(xz + hz)));
          float ngate = tanhf(xn + rgate * hn);
          size_t ho = (size_t)row * HSZ + col;
          float h_old = P.HF32[ho];
          float hg = (1.f - zgate) * ngate + zgate * h_old;
          float hnew = h_old * om + alpha * hg;
          P.HF32[ho] = hnew; P.HF16[ho] = (_Float16)hnew;
          float c_old = P.CF32[ho];
          float cin_t = (float)P.CIN[((size_t)t * BSZ + row) * HSZ + col];
          float cnew = (c_old * nom + cin_t) / nnew;
          P.CF32[ho] = cnew;
          P.COM[(size_t)row * HH2 + col] = (_Float16)cnew;
          if (t + 1 < SLEN)
            P.COM[(size_t)row * HH2 + 512 + col] =
                P.CIN[((size_t)(t + 1) * BSZ + row) * HSZ + col];
        }
      }
      blk_arrive(CTE);
    }

    // ---- tail (gate blocks only): final GRU + output ----
    blk_wait(CTE, 64u * (unsigned)SLEN);
#pragma unroll
    for (int s = 0; s < 3; ++s) {
      int g = 3 * i + s;
      bool ih = (g < 96);
      int gl = ih ? g : g - 96;
      int cg = 16 * gl + ml;
      f4 a = ih ? gemm_tile<512>(P.COM, HH2, sm + s * 8320, 520, wv * 16, ml, q)
                : gemm_tile<512>(P.HF16, HSZ, sm + s * 8320, 520, wv * 16, ml, q);
      float bia = ih ? P.b_ih[cg] : P.b_hh[cg];
      float* dst = ih ? P.GX : P.GH;
#pragma unroll
      for (int r = 0; r < 4; ++r)
        dst[(size_t)(wv * 16 + q * 4 + r) * GG3 + cg] = a[r] + bia;
    }
    blk_arrive(CTD);
    blk_wait(CTD, 64u * (unsigned)(SLEN + 1));
    __syncthreads();  // LDS weights no longer needed; reuse sm as float hfin[2][512]
    {
      float* hf = (float*)sm;
      const int col = tid;
#pragma unroll
      for (int rr = 0; rr < 2; ++rr) {
        int row = 2 * i + rr;
        size_t go = (size_t)row * GG3 + col;
        float xr = P.GX[go], xz = P.GX[go + 512], xn = P.GX[go + 1024];
        float hr = P.GH[go], hz = P.GH[go + 512], hn = P.GH[go + 1024];
        float rgate = 1.f / (1.f + expf(-(xr + hr)));
        float zgate = 1.f / (1.f + expf(-(xz + hz)));
        float ngate = tanhf(xn + rgate * hn);
        float h_old = P.HF32[(size_t)row * HSZ + col];
        hf[rr * 512 + col] = (1.f - zgate) * ngate + zgate * h_old;
      }
    }
    __syncthreads();
    if (wv < 2) {
      const float* hf = (const float*)sm;
      int row = 2 * i + wv;
      float accs[OSZ];
#pragma unroll
      for (int c = 0; c < OSZ; ++c) accs[c] = 0.f;
#pragma unroll
      for (int j = 0; j < 8; ++j) {
        float hv = hf[wv * 512 + lane * 8 + j];
        const float* wr = P.w_out + (size_t)(lane * 8 + j) * OSZ;
#pragma unroll
        for (int c = 0; c < OSZ; ++c) accs[c] += hv * wr[c];
      }
#pragma unroll
      for (int c = 0; c < OSZ; ++c) {
        float v = accs[c];
#pragma unroll
        for (int off = 32; off > 0; off >>= 1) v += __shfl_xor(v, off);
        if (lane == 0) P.out[row * OSZ + c] = v + P.b_out[c];
      }
    }
  }
}

// ---------------- host ----------------
extern "C" void kernel_launch(void* const* d_in, const int* in_sizes, int n_in,
                              void* d_out, int out_size, void* d_ws, size_t ws_size,
                              hipStream_t stream) {
  const float* x     = (const float*)d_in[0];
  const float* noise = (const float*)d_in[1];
  const float* w_cin = (const float*)d_in[2];
  const float* b_cin = (const float*)d_in[3];
  const float* w1    = (const float*)d_in[4];
  const float* b1    = (const float*)d_in[5];
  const float* w2    = (const float*)d_in[6];
  const float* b2    = (const float*)d_in[7];
  const float* w3    = (const float*)d_in[8];
  const float* b3    = (const float*)d_in[9];
  const float* w4    = (const float*)d_in[10];
  const float* b4    = (const float*)d_in[11];
  const float* w_ih  = (const float*)d_in[12];
  const float* b_ih  = (const float*)d_in[13];
  const float* w_hh  = (const float*)d_in[14];
  const float* b_hh  = (const float*)d_in[15];
  const float* w_out = (const float*)d_in[16];
  const float* b_out = (const float*)d_in[17];

  char* ws = (char*)d_ws;
  size_t off = 0;
  auto alloc = [&](size_t bytes) -> void* {
    void* p = ws + off;
    off = (off + bytes + 255) & ~(size_t)255;
    return p;
  };

  P_t P;
  P.x = x; P.noise = noise; P.b_cin = b_cin; P.b1 = b1; P.b2 = b2; P.b3 = b3;
  P.w4 = w4; P.b4 = b4; P.b_ih = b_ih; P.b_hh = b_hh; P.w_out = w_out; P.b_out = b_out;
  P.WT1   = (_Float16*)alloc((size_t)HH2 * HH2 * 2);
  P.WT2   = (_Float16*)alloc((size_t)HH2 * HH2 * 2);
  P.WT3   = (_Float16*)alloc((size_t)HH2 * HH2 * 2);
  P.WTih  = (_Float16*)alloc((size_t)GG3 * HSZ * 2);
  P.WThh  = (_Float16*)alloc((size_t)GG3 * HSZ * 2);
  P.WTcin = (_Float16*)alloc((size_t)HSZ * DIN * 2);
  P.CIN   = (_Float16*)alloc((size_t)SLEN * BSZ * HSZ * 2);
  P.COM   = (_Float16*)alloc((size_t)BSZ * HH2 * 2);
  P.Z1    = (_Float16*)alloc((size_t)BSZ * HH2 * 2);
  P.Z2    = (_Float16*)alloc((size_t)BSZ * HH2 * 2);
  P.HF16  = (_Float16*)alloc((size_t)BSZ * HSZ * 2);
  P.LOGI  = (float*)alloc((size_t)SLEN * BSZ * 4);
  P.GX    = (float*)alloc((size_t)BSZ * GG3 * 4);
  P.GH    = (float*)alloc((size_t)BSZ * GG3 * 4);
  P.PART  = (float*)alloc((size_t)64 * BSZ * 4);
  P.HF32  = (float*)alloc((size_t)BSZ * HSZ * 4);
  P.CF32  = (float*)alloc((size_t)BSZ * HSZ * 4);
  P.NF32  = (float*)alloc((size_t)BSZ * 4);
  P.CTR   = (unsigned*)alloc(512 * 4);
  P.out   = (float*)d_out;

  transpose_cvt<<<(HH2 / 32) * (HH2 / 32), 256, 0, stream>>>(w1, P.WT1, HH2, HH2);
  transpose_cvt<<<(HH2 / 32) * (HH2 / 32), 256, 0, stream>>>(w2, P.WT2, HH2, HH2);
  transpose_cvt<<<(HH2 / 32) * (HH2 / 32), 256, 0, stream>>>(w3, P.WT3, HH2, HH2);
  transpose_cvt<<<(GG3 / 32) * (HSZ / 32), 256, 0, stream>>>(w_ih, P.WTih, HSZ, GG3);
  transpose_cvt<<<(GG3 / 32) * (HSZ / 32), 256, 0, stream>>>(w_hh, P.WThh, HSZ, GG3);
  transpose_cvt<<<(HSZ / 32) * (DIN / 32), 256, 0, stream>>>(w_cin, P.WTcin, DIN, HSZ);

  cin_kernel<<<1024, 256, 0, stream>>>(P);
  init_kernel<<<256, 256, 0, stream>>>(P);
  rnn_main<<<NBLK, NTHR, 0, stream>>>(P);
}

// Round 6
// 11951.011 us; speedup vs baseline: 2.4196x; 1.2052x over previous
//
#include <hip/hip_runtime.h>
#include <math.h>

// Problem dims
#define SLEN 256
#define BSZ  128
#define DIN  128
#define HSZ  512
#define HH2  1024
#define GG3  1536
#define OSZ  25

typedef _Float16 h8 __attribute__((ext_vector_type(8)));
typedef float    f4 __attribute__((ext_vector_type(4)));

// Dataflow-pipeline geometry: 256 blocks x 512 threads, 1 block/CU.
// Roles: b<64: W1 | b<128: W2 | b<192: W3(+PART) | b<256: gates(+P4)
#define NBLK 256
#define NTHR 512

// LDS (f16 units), fragment-major B layout [K/32][64 lanes][8]:
//   W-tile 16x1024 -> 32*512 = 16384 f16 (32 KB)
//   3 gate tiles 16x512 -> 3*16*512 = 24576 f16 (48 KB)
#define SM_F16 24576

// Barrier counters: 5 barriers x 16 subs x 32-dword stride (128B lines)
#define CSUB 32
#define CBAR (16 * CSUB)   // 512 dwords per barrier
#define NCTR (5 * CBAR)    // 2560 dwords total

struct P_t {
  const float *x, *noise, *b_cin, *b1, *b2, *b3, *w4, *b4, *b_ih, *b_hh, *w_out, *b_out;
  _Float16 *WT1, *WT2, *WT3, *WTih, *WThh, *WTcin;  // f16 transposed [N][K]
  _Float16 *CIN, *COM, *Z1, *Z2, *HF16;
  float *LOGI, *GX, *GH, *PART, *HF32, *CF32, *NF32;
  unsigned *CTR;
  float *out;
};

// ---------------- split device barrier, 16-way distributed counters ----------------
// Arrive: block b bumps sub-counter (b&15); 4 arrivals/sub/step (64 blocks/role).
__device__ __forceinline__ void blk_arrive16(unsigned* base, int sub) {
  __syncthreads();
  if (threadIdx.x == 0) { __threadfence(); atomicAdd(base + sub * CSUB, 1u); }
}
// Wait: lanes 0..15 of wave 0 each poll one sub-counter until >= target.
__device__ __forceinline__ void blk_wait16(unsigned* base, unsigned target) {
  if (threadIdx.x < 16) {
    unsigned* p = base + threadIdx.x * CSUB;
    while (__hip_atomic_load(p, __ATOMIC_RELAXED, __HIP_MEMORY_SCOPE_AGENT) < target)
      __builtin_amdgcn_s_sleep(2);
  }
  if (threadIdx.x == 0) __threadfence();
  __syncthreads();
}

// 16x16 MFMA tile: A [M,K] f16 global row-major; B fragment-major in LDS:
// Bs[(k/32)*512 + lane*8 + j] == BT[n0 + (lane&15)][k + (lane>>4)*8 + j].
template<int K>
__device__ __forceinline__ f4 gemm_tile(const _Float16* __restrict__ A, int lda,
                                        const _Float16* __restrict__ Bs,
                                        int m0, int ml, int q, int lane) {
  const _Float16* ap = A + (size_t)(m0 + ml) * lda + q * 8;
  const _Float16* bp = Bs + lane * 8;
  f4 acc = {0.f, 0.f, 0.f, 0.f};
#pragma unroll
  for (int k = 0; k < K; k += 32)
    acc = __builtin_amdgcn_mfma_f32_16x16x32_f16(*(const h8*)(ap + k),
                                                 *(const h8*)(bp + (k >> 5) * 512),
                                                 acc, 0, 0, 0);
  return acc;
}

// ---------------- setup kernels (R2-proven) ----------------
__global__ __launch_bounds__(256) void transpose_cvt(const float* __restrict__ src,
    _Float16* __restrict__ dst, int K, int N) {
  __shared__ float tl[32][33];
  int nt = N >> 5;
  int bx = blockIdx.x % nt, by = blockIdx.x / nt;
  int n0 = bx << 5, k0 = by << 5;
  int tx = threadIdx.x & 31, ty = threadIdx.x >> 5;
#pragma unroll
  for (int i = 0; i < 4; ++i) {
    int r = ty + (i << 3);
    tl[r][tx] = src[(size_t)(k0 + r) * N + n0 + tx];
  }
  __syncthreads();
#pragma unroll
  for (int i = 0; i < 4; ++i) {
    int r = ty + (i << 3);
    dst[(size_t)(n0 + r) * K + k0 + tx] = (_Float16)tl[tx][r];
  }
}

__global__ __launch_bounds__(256) void cin_kernel(P_t P) {
  int tid = blockIdx.x * blockDim.x + threadIdx.x;
  if (tid < SLEN * BSZ) {
    float u = P.noise[tid];
    P.LOGI[tid] = logf(u) - log1pf(-u);
  }
  int gw = tid >> 6, lane = tid & 63;
  int nw = (gridDim.x * blockDim.x) >> 6;
  int ml = lane & 15, q = lane >> 4;
  const int MT = (SLEN * BSZ) / 16;
  for (int tt = gw; tt < MT * 8; tt += nw) {
    int mt = tt & (MT - 1), nt = tt / MT;
    int m0 = mt * 16, n0 = nt * 64;
    int m = m0 + ml, b = m & 127, s = m >> 7;
    const float* ap = P.x + ((size_t)b * SLEN + s) * DIN + q * 8;
    const _Float16* bp = P.WTcin + (size_t)(n0 + ml) * DIN + q * 8;
    f4 a0 = {0,0,0,0}, a1 = a0, a2 = a0, a3 = a0;
#pragma unroll
    for (int k = 0; k < DIN; k += 32) {
      f4 lo = *(const f4*)(ap + k);
      f4 hi = *(const f4*)(ap + k + 4);
      h8 av;
      av[0] = (_Float16)lo[0]; av[1] = (_Float16)lo[1];
      av[2] = (_Float16)lo[2]; av[3] = (_Float16)lo[3];
      av[4] = (_Float16)hi[0]; av[5] = (_Float16)hi[1];
      av[6] = (_Float16)hi[2]; av[7] = (_Float16)hi[3];
      a0 = __builtin_amdgcn_mfma_f32_16x16x32_f16(av, *(const h8*)(bp + k),          a0, 0,0,0);
      a1 = __builtin_amdgcn_mfma_f32_16x16x32_f16(av, *(const h8*)(bp + 16*DIN + k), a1, 0,0,0);
      a2 = __builtin_amdgcn_mfma_f32_16x16x32_f16(av, *(const h8*)(bp + 32*DIN + k), a2, 0,0,0);
      a3 = __builtin_amdgcn_mfma_f32_16x16x32_f16(av, *(const h8*)(bp + 48*DIN + k), a3, 0,0,0);
    }
#pragma unroll
    for (int r = 0; r < 4; ++r) {
      int row = m0 + q * 4 + r;
      int c0 = n0 + ml;
      P.CIN[(size_t)row * HSZ + c0     ] = (_Float16)tanhf(a0[r] + P.b_cin[c0]);
      P.CIN[(size_t)row * HSZ + c0 + 16] = (_Float16)tanhf(a1[r] + P.b_cin[c0 + 16]);
      P.CIN[(size_t)row * HSZ + c0 + 32] = (_Float16)tanhf(a2[r] + P.b_cin[c0 + 32]);
      P.CIN[(size_t)row * HSZ + c0 + 48] = (_Float16)tanhf(a3[r] + P.b_cin[c0 + 48]);
    }
  }
}

__global__ __launch_bounds__(256) void init_kernel(P_t P) {
  int idx = blockIdx.x * 256 + threadIdx.x;
  if (idx < BSZ * HSZ) {
    int row = idx >> 9, i = idx & 511;
    P.CF32[idx] = 0.f; P.HF32[idx] = 0.f; P.HF16[idx] = (_Float16)0.f;
    P.COM[(size_t)row * HH2 + i] = (_Float16)0.f;
    P.COM[(size_t)row * HH2 + 512 + i] = P.CIN[idx];
  }
  if (idx < BSZ) P.NF32[idx] = 0.f;
  if (idx < NCTR) P.CTR[idx] = 0u;
}

// ---------------- main persistent dataflow kernel ----------------
__global__ __launch_bounds__(NTHR) void rnn_main(P_t P) {
  __shared__ __align__(16) _Float16 sm[SM_F16];
  __shared__ float sred[8];
  const int tid = threadIdx.x;
  const int b = blockIdx.x;
  const int lane = tid & 63;
  const int wv = tid >> 6;           // 0..7
  const int ml = lane & 15, q = lane >> 4;
  const int sub = b & 15;

  unsigned* CTA = P.CTR;             // z1 ready       (64 W1 arrivals -> 4/sub)
  unsigned* CTB = P.CTR + CBAR;      // z2 ready
  unsigned* CTC = P.CTR + 2*CBAR;    // PART ready
  unsigned* CTD = P.CTR + 3*CBAR;    // gx/gh ready
  unsigned* CTE = P.CTR + 4*CBAR;    // state updated

  // ---- stage this block's weight slice into LDS, fragment-major ----
  if (b < 192) {
    const _Float16* W = (b < 64) ? P.WT1 : (b < 128) ? P.WT2 : P.WT3;
    const int j16 = b & 63;
#pragma unroll
    for (int rep = 0; rep < 4; ++rep) {
      int idx = tid + rep * 512;          // 0..2047 chunks of 8
      int kk = idx >> 6, ln = idx & 63;
      int mlw = ln & 15, qw = ln >> 4;
      *(h8*)(sm + idx * 8) =
          *(const h8*)(W + (size_t)(16 * j16 + mlw) * HH2 + kk * 32 + qw * 8);
    }
  } else {
    const int i = b - 192;
#pragma unroll
    for (int s = 0; s < 3; ++s) {
      int g = 3 * i + s;
      const _Float16* src = (g < 96) ? (P.WTih + (size_t)(16 * g) * HSZ)
                                     : (P.WThh + (size_t)(16 * (g - 96)) * HSZ);
#pragma unroll
      for (int rep = 0; rep < 2; ++rep) {
        int idx = tid + rep * 512;        // 0..1023 chunks of 8
        int kk = idx >> 6, ln = idx & 63;
        int mlw = ln & 15, qw = ln >> 4;
        *(h8*)(sm + s * 8192 + idx * 8) =
            *(const h8*)(src + (size_t)mlw * HSZ + kk * 32 + qw * 8);
      }
    }
  }
  __syncthreads();

  if (b < 64) {
    // ---- W1 role: z1 = relu(com @ W1 + b1), own cols 16b..16b+15 ----
    const int colb = 16 * b + ml;
    const float bia = P.b1[colb];
    for (int t = 0; t < SLEN; ++t) {
      blk_wait16(CTE, 4u * (unsigned)t);
      f4 a = gemm_tile<1024>(P.COM, HH2, sm, wv * 16, ml, q, lane);
#pragma unroll
      for (int r = 0; r < 4; ++r)
        P.Z1[(size_t)(wv * 16 + q * 4 + r) * HH2 + colb] = (_Float16)fmaxf(a[r] + bia, 0.f);
      blk_arrive16(CTA, sub);
    }
  } else if (b < 128) {
    // ---- W2 role: z2 = relu(z1 @ W2 + b2) ----
    const int colb = 16 * (b - 64) + ml;
    const float bia = P.b2[colb];
    for (int t = 0; t < SLEN; ++t) {
      blk_wait16(CTA, 4u * (unsigned)(t + 1));
      f4 a = gemm_tile<1024>(P.Z1, HH2, sm, wv * 16, ml, q, lane);
#pragma unroll
      for (int r = 0; r < 4; ++r)
        P.Z2[(size_t)(wv * 16 + q * 4 + r) * HH2 + colb] = (_Float16)fmaxf(a[r] + bia, 0.f);
      blk_arrive16(CTB, sub);
    }
  } else if (b < 192) {
    // ---- W3 role: z3 tile, fold w4-dot into PART[k][row] ----
    const int k = b - 128;
    const int colb = 16 * k + ml;
    const float bia = P.b3[colb];
    const float w4v = P.w4[colb];
    for (int t = 0; t < SLEN; ++t) {
      blk_wait16(CTB, 4u * (unsigned)(t + 1));
      f4 a = gemm_tile<1024>(P.Z2, HH2, sm, wv * 16, ml, q, lane);
#pragma unroll
      for (int r = 0; r < 4; ++r) {
        float v = fmaxf(a[r] + bia, 0.f) * w4v;
        v += __shfl_xor(v, 1); v += __shfl_xor(v, 2);
        v += __shfl_xor(v, 4); v += __shfl_xor(v, 8);
        if (ml == 0) P.PART[(size_t)k * BSZ + wv * 16 + q * 4 + r] = v;
      }
      blk_arrive16(CTC, sub);
    }
  } else {
    // ---- gate role: gx/gh GEMMs, then alpha + state update for rows 2i,2i+1 ----
    const int i = b - 192;
    for (int t = 0; t < SLEN; ++t) {
      blk_wait16(CTE, 4u * (unsigned)t);
#pragma unroll
      for (int s = 0; s < 3; ++s) {
        int g = 3 * i + s;
        bool ih = (g < 96);
        int gl = ih ? g : g - 96;
        int cg = 16 * gl + ml;
        f4 a = ih ? gemm_tile<512>(P.COM, HH2, sm + s * 8192, wv * 16, ml, q, lane)
                  : gemm_tile<512>(P.HF16, HSZ, sm + s * 8192, wv * 16, ml, q, lane);
        float bia = ih ? P.b_ih[cg] : P.b_hh[cg];
        float* dst = ih ? P.GX : P.GH;
#pragma unroll
        for (int r = 0; r < 4; ++r)
          dst[(size_t)(wv * 16 + q * 4 + r) * GG3 + cg] = a[r] + bia;
      }
      blk_arrive16(CTD, sub);
      blk_wait16(CTC, 4u * (unsigned)(t + 1));
      blk_wait16(CTD, 4u * (unsigned)(t + 1));
      // alpha for rows 2i, 2i+1
      if (wv < 2) {
        int row = 2 * i + wv;
        float v = P.PART[(size_t)lane * BSZ + row];
#pragma unroll
        for (int off = 32; off > 0; off >>= 1) v += __shfl_xor(v, off);
        if (lane == 0) {
          float lg = (v + P.b4[0] + P.LOGI[t * BSZ + row]) * 10.0f;
          float alpha = 1.f / (1.f + expf(-lg));
          float om = 1.f - alpha;
          float n_old = P.NF32[row];
          float nnew = n_old * om + 1.f;
          P.NF32[row] = nnew;
          sred[wv * 4 + 0] = alpha; sred[wv * 4 + 1] = om;
          sred[wv * 4 + 2] = n_old * om; sred[wv * 4 + 3] = nnew;
        }
      }
      __syncthreads();
      {
        const int col = tid;  // 0..511
#pragma unroll
        for (int rr = 0; rr < 2; ++rr) {
          int row = 2 * i + rr;
          float alpha = sred[rr * 4], om = sred[rr * 4 + 1];
          float nom = sred[rr * 4 + 2], nnew = sred[rr * 4 + 3];
          size_t go = (size_t)row * GG3 + col;
          float xr = P.GX[go], xz = P.GX[go + 512], xn = P.GX[go + 1024];
          float hr = P.GH[go], hz = P.GH[go + 512], hn = P.GH[go + 1024];
          float rgate = 1.f / (1.f + expf(-(xr + hr)));
          float zgate = 1.f / (1.f + expf(-(xz + hz)));
          float ngate = tanhf(xn + rgate * hn);
          size_t ho = (size_t)row * HSZ + col;
          float h_old = P.HF32[ho];
          float hg = (1.f - zgate) * ngate + zgate * h_old;
          float hnew = h_old * om + alpha * hg;
          P.HF32[ho] = hnew; P.HF16[ho] = (_Float16)hnew;
          float c_old = P.CF32[ho];
          float cin_t = (float)P.CIN[((size_t)t * BSZ + row) * HSZ + col];
          float cnew = (c_old * nom + cin_t) / nnew;
          P.CF32[ho] = cnew;
          P.COM[(size_t)row * HH2 + col] = (_Float16)cnew;
          if (t + 1 < SLEN)
            P.COM[(size_t)row * HH2 + 512 + col] =
                P.CIN[((size_t)(t + 1) * BSZ + row) * HSZ + col];
        }
      }
      blk_arrive16(CTE, sub);
    }

    // ---- tail (gate blocks only): final GRU + output ----
    blk_wait16(CTE, 4u * (unsigned)SLEN);
#pragma unroll
    for (int s = 0; s < 3; ++s) {
      int g = 3 * i + s;
      bool ih = (g < 96);
      int gl = ih ? g : g - 96;
      int cg = 16 * gl + ml;
      f4 a = ih ? gemm_tile<512>(P.COM, HH2, sm + s * 8192, wv * 16, ml, q, lane)
                : gemm_tile<512>(P.HF16, HSZ, sm + s * 8192, wv * 16, ml, q, lane);
      float bia = ih ? P.b_ih[cg] : P.b_hh[cg];
      float* dst = ih ? P.GX : P.GH;
#pragma unroll
      for (int r = 0; r < 4; ++r)
        dst[(size_t)(wv * 16 + q * 4 + r) * GG3 + cg] = a[r] + bia;
    }
    blk_arrive16(CTD, sub);
    blk_wait16(CTD, 4u * (unsigned)(SLEN + 1));
    __syncthreads();  // LDS weights no longer needed; reuse sm as float hfin[2][512]
    {
      float* hf = (float*)sm;
      const int col = tid;
#pragma unroll
      for (int rr = 0; rr < 2; ++rr) {
        int row = 2 * i + rr;
        size_t go = (size_t)row * GG3 + col;
        float xr = P.GX[go], xz = P.GX[go + 512], xn = P.GX[go + 1024];
        float hr = P.GH[go], hz = P.GH[go + 512], hn = P.GH[go + 1024];
        float rgate = 1.f / (1.f + expf(-(xr + hr)));
        float zgate = 1.f / (1.f + expf(-(xz + hz)));
        float ngate = tanhf(xn + rgate * hn);
        float h_old = P.HF32[(size_t)row * HSZ + col];
        hf[rr * 512 + col] = (1.f - zgate) * ngate + zgate * h_old;
      }
    }
    __syncthreads();
    if (wv < 2) {
      const float* hf = (const float*)sm;
      int row = 2 * i + wv;
      float accs[OSZ];
#pragma unroll
      for (int c = 0; c < OSZ; ++c) accs[c] = 0.f;
#pragma unroll
      for (int j = 0; j < 8; ++j) {
        float hv = hf[wv * 512 + lane * 8 + j];
        const float* wr = P.w_out + (size_t)(lane * 8 + j) * OSZ;
#pragma unroll
        for (int c = 0; c < OSZ; ++c) accs[c] += hv * wr[c];
      }
#pragma unroll
      for (int c = 0; c < OSZ; ++c) {
        float v = accs[c];
#pragma unroll
        for (int off = 32; off > 0; off >>= 1) v += __shfl_xor(v, off);
        if (lane == 0) P.out[row * OSZ + c] = v + P.b_out[c];
      }
    }
  }
}

// ---------------- host ----------------
extern "C" void kernel_launch(void* const* d_in, const int* in_sizes, int n_in,
                              void* d_out, int out_size, void* d_ws, size_t ws_size,
                              hipStream_t stream) {
  const float* x     = (const float*)d_in[0];
  const float* noise = (const float*)d_in[1];
  const float* w_cin = (const float*)d_in[2];
  const float* b_cin = (const float*)d_in[3];
  const float* w1    = (const float*)d_in[4];
  const float* b1    = (const float*)d_in[5];
  const float* w2    = (const float*)d_in[6];
  const float* b2    = (const float*)d_in[7];
  const float* w3    = (const float*)d_in[8];
  const float* b3    = (const float*)d_in[9];
  const float* w4    = (const float*)d_in[10];
  const float* b4    = (const float*)d_in[11];
  const float* w_ih  = (const float*)d_in[12];
  const float* b_ih  = (const float*)d_in[13];
  const float* w_hh  = (const float*)d_in[14];
  const float* b_hh  = (const float*)d_in[15];
  const float* w_out = (const float*)d_in[16];
  const float* b_out = (const float*)d_in[17];

  char* ws = (char*)d_ws;
  size_t off = 0;
  auto alloc = [&](size_t bytes) -> void* {
    void* p = ws + off;
    off = (off + bytes + 255) & ~(size_t)255;
    return p;
  };

  P_t P;
  P.x = x; P.noise = noise; P.b_cin = b_cin; P.b1 = b1; P.b2 = b2; P.b3 = b3;
  P.w4 = w4; P.b4 = b4; P.b_ih = b_ih; P.b_hh = b_hh; P.w_out = w_out; P.b_out = b_out;
  P.WT1   = (_Float16*)alloc((size_t)HH2 * HH2 * 2);
  P.WT2   = (_Float16*)alloc((size_t)HH2 * HH2 * 2);
  P.WT3   = (_Float16*)alloc((size_t)HH2 * HH2 * 2);
  P.WTih  = (_Float16*)alloc((size_t)GG3 * HSZ * 2);
  P.WThh  = (_Float16*)alloc((size_t)GG3 * HSZ * 2);
  P.WTcin = (_Float16*)alloc((size_t)HSZ * DIN * 2);
  P.CIN   = (_Float16*)alloc((size_t)SLEN * BSZ * HSZ * 2);
  P.COM   = (_Float16*)alloc((size_t)BSZ * HH2 * 2);
  P.Z1    = (_Float16*)alloc((size_t)BSZ * HH2 * 2);
  P.Z2    = (_Float16*)alloc((size_t)BSZ * HH2 * 2);
  P.HF16  = (_Float16*)alloc((size_t)BSZ * HSZ * 2);
  P.LOGI  = (float*)alloc((size_t)SLEN * BSZ * 4);
  P.GX    = (float*)alloc((size_t)BSZ * GG3 * 4);
  P.GH    = (float*)alloc((size_t)BSZ * GG3 * 4);
  P.PART  = (float*)alloc((size_t)64 * BSZ * 4);
  P.HF32  = (float*)alloc((size_t)BSZ * HSZ * 4);
  P.CF32  = (float*)alloc((size_t)BSZ * HSZ * 4);
  P.NF32  = (float*)alloc((size_t)BSZ * 4);
  P.CTR   = (unsigned*)alloc(NCTR * 4);
  P.out   = (float*)d_out;

  transpose_cvt<<<(HH2 / 32) * (HH2 / 32), 256, 0, stream>>>(w1, P.WT1, HH2, HH2);
  transpose_cvt<<<(HH2 / 32) * (HH2 / 32), 256, 0, stream>>>(w2, P.WT2, HH2, HH2);
  transpose_cvt<<<(HH2 / 32) * (HH2 / 32), 256, 0, stream>>>(w3, P.WT3, HH2, HH2);
  transpose_cvt<<<(GG3 / 32) * (HSZ / 32), 256, 0, stream>>>(w_ih, P.WTih, HSZ, GG3);
  transpose_cvt<<<(GG3 / 32) * (HSZ / 32), 256, 0, stream>>>(w_hh, P.WThh, HSZ, GG3);
  transpose_cvt<<<(HSZ / 32) * (DIN / 32), 256, 0, stream>>>(w_cin, P.WTcin, DIN, HSZ);

  cin_kernel<<<1024, 256, 0, stream>>>(P);
  init_kernel<<<256, 256, 0, stream>>>(P);
  rnn_main<<<NBLK, NTHR, 0, stream>>>(P);
}

// Round 7
// 11071.646 us; speedup vs baseline: 2.6118x; 1.0794x over previous
//
#include <hip/hip_runtime.h>
#include <math.h>

// Problem dims
#define SLEN 256
#define BSZ  128
#define DIN  128
#define HSZ  512
#define HH2  1024
#define GG3  1536
#define OSZ  25

typedef _Float16 h8 __attribute__((ext_vector_type(8)));
typedef float    f4 __attribute__((ext_vector_type(4)));

// Dataflow-pipeline geometry: 256 blocks x 1024 threads (16 waves), 1 block/CU.
// Roles: b<64: W1 | b<128: W2 | b<192: W3(+PART) | b<256: gates(+state)
#define NBLK 256
#define NTHR 1024

// LDS (f16 units), fragment-major B layout [K/32][64 lanes][8]:
//   W-tile 16x1024 -> 16384 f16 (32 KB); 3 gate tiles 16x512 -> 24576 f16 (48 KB)
#define SM_F16 24576

// Barrier counters: 5 barriers x 16 subs x 32-dword stride (128B lines)
#define CSUB 32
#define CBAR (16 * CSUB)
#define NCTR (5 * CBAR)

struct P_t {
  const float *x, *noise, *b_cin, *b1, *b2, *b3, *w4, *b4, *b_ih, *b_hh, *w_out, *b_out;
  _Float16 *WT1, *WT2, *WT3, *WTih, *WThh, *WTcin;  // f16 transposed [N][K]
  _Float16 *CIN, *COM, *Z1, *Z2, *HF16;
  float *LOGI, *GX, *GH, *PART, *HF32, *CF32, *NF32;
  unsigned *CTR;
  float *out;
};

// ---------------- split device barrier: release-arrive / acquire-wait ----------------
__device__ __forceinline__ void blk_arrive16(unsigned* base, int sub) {
  __syncthreads();
  if (threadIdx.x == 0) {
    __builtin_amdgcn_fence(__ATOMIC_RELEASE, "agent");   // wbl2 only
    atomicAdd(base + sub * CSUB, 1u);
  }
}
__device__ __forceinline__ void blk_wait16(unsigned* base, unsigned target) {
  if (threadIdx.x < 16) {
    unsigned* p = base + threadIdx.x * CSUB;
    while (__hip_atomic_load(p, __ATOMIC_RELAXED, __HIP_MEMORY_SCOPE_AGENT) < target)
      __builtin_amdgcn_s_sleep(2);
  }
  if (threadIdx.x == 0)
    __builtin_amdgcn_fence(__ATOMIC_ACQUIRE, "agent");   // inv only
  __syncthreads();
}

// 16x16xK MFMA fragment GEMM. A [M,lda] f16 global row-major starting at col k0;
// B fragment-major in LDS: Bs[(k/32)*512 + lane*8 + j].
template<int K>
__device__ __forceinline__ f4 gemm_frag(const _Float16* __restrict__ A, int lda, int k0,
                                        const _Float16* __restrict__ Bs,
                                        int m0, int ml, int q, int lane) {
  const _Float16* ap = A + (size_t)(m0 + ml) * lda + k0 + q * 8;
  const _Float16* bp = Bs + (k0 >> 5) * 512 + lane * 8;
  f4 acc = {0.f, 0.f, 0.f, 0.f};
#pragma unroll
  for (int k = 0; k < K; k += 32)
    acc = __builtin_amdgcn_mfma_f32_16x16x32_f16(*(const h8*)(ap + k),
                                                 *(const h8*)(bp + (k >> 5) * 512),
                                                 acc, 0, 0, 0);
  return acc;
}

// Dual-B variant: reuse the A fragment stream for two B tiles (gate gx/gh).
template<int K>
__device__ __forceinline__ void gemm_frag2(const _Float16* __restrict__ A, int lda,
                                           const _Float16* __restrict__ Bs0,
                                           const _Float16* __restrict__ Bs1,
                                           int m0, int ml, int q, int lane,
                                           f4& o0, f4& o1) {
  const _Float16* ap = A + (size_t)(m0 + ml) * lda + q * 8;
  const _Float16* b0 = Bs0 + lane * 8;
  const _Float16* b1 = Bs1 + lane * 8;
  f4 x = {0.f, 0.f, 0.f, 0.f}, y = x;
#pragma unroll
  for (int k = 0; k < K; k += 32) {
    h8 av = *(const h8*)(ap + k);
    x = __builtin_amdgcn_mfma_f32_16x16x32_f16(av, *(const h8*)(b0 + (k >> 5) * 512), x, 0, 0, 0);
    y = __builtin_amdgcn_mfma_f32_16x16x32_f16(av, *(const h8*)(b1 + (k >> 5) * 512), y, 0, 0, 0);
  }
  o0 = x; o1 = y;
}

// ---------------- setup kernels (R2-proven) ----------------
__global__ __launch_bounds__(256) void transpose_cvt(const float* __restrict__ src,
    _Float16* __restrict__ dst, int K, int N) {
  __shared__ float tl[32][33];
  int nt = N >> 5;
  int bx = blockIdx.x % nt, by = blockIdx.x / nt;
  int n0 = bx << 5, k0 = by << 5;
  int tx = threadIdx.x & 31, ty = threadIdx.x >> 5;
#pragma unroll
  for (int i = 0; i < 4; ++i) {
    int r = ty + (i << 3);
    tl[r][tx] = src[(size_t)(k0 + r) * N + n0 + tx];
  }
  __syncthreads();
#pragma unroll
  for (int i = 0; i < 4; ++i) {
    int r = ty + (i << 3);
    dst[(size_t)(n0 + r) * K + k0 + tx] = (_Float16)tl[tx][r];
  }
}

__global__ __launch_bounds__(256) void cin_kernel(P_t P) {
  int tid = blockIdx.x * blockDim.x + threadIdx.x;
  if (tid < SLEN * BSZ) {
    float u = P.noise[tid];
    P.LOGI[tid] = logf(u) - log1pf(-u);
  }
  int gw = tid >> 6, lane = tid & 63;
  int nw = (gridDim.x * blockDim.x) >> 6;
  int ml = lane & 15, q = lane >> 4;
  const int MT = (SLEN * BSZ) / 16;
  for (int tt = gw; tt < MT * 8; tt += nw) {
    int mt = tt & (MT - 1), nt = tt / MT;
    int m0 = mt * 16, n0 = nt * 64;
    int m = m0 + ml, b = m & 127, s = m >> 7;
    const float* ap = P.x + ((size_t)b * SLEN + s) * DIN + q * 8;
    const _Float16* bp = P.WTcin + (size_t)(n0 + ml) * DIN + q * 8;
    f4 a0 = {0,0,0,0}, a1 = a0, a2 = a0, a3 = a0;
#pragma unroll
    for (int k = 0; k < DIN; k += 32) {
      f4 lo = *(const f4*)(ap + k);
      f4 hi = *(const f4*)(ap + k + 4);
      h8 av;
      av[0] = (_Float16)lo[0]; av[1] = (_Float16)lo[1];
      av[2] = (_Float16)lo[2]; av[3] = (_Float16)lo[3];
      av[4] = (_Float16)hi[0]; av[5] = (_Float16)hi[1];
      av[6] = (_Float16)hi[2]; av[7] = (_Float16)hi[3];
      a0 = __builtin_amdgcn_mfma_f32_16x16x32_f16(av, *(const h8*)(bp + k),          a0, 0,0,0);
      a1 = __builtin_amdgcn_mfma_f32_16x16x32_f16(av, *(const h8*)(bp + 16*DIN + k), a1, 0,0,0);
      a2 = __builtin_amdgcn_mfma_f32_16x16x32_f16(av, *(const h8*)(bp + 32*DIN + k), a2, 0,0,0);
      a3 = __builtin_amdgcn_mfma_f32_16x16x32_f16(av, *(const h8*)(bp + 48*DIN + k), a3, 0,0,0);
    }
#pragma unroll
    for (int r = 0; r < 4; ++r) {
      int row = m0 + q * 4 + r;
      int c0 = n0 + ml;
      P.CIN[(size_t)row * HSZ + c0     ] = (_Float16)tanhf(a0[r] + P.b_cin[c0]);
      P.CIN[(size_t)row * HSZ + c0 + 16] = (_Float16)tanhf(a1[r] + P.b_cin[c0 + 16]);
      P.CIN[(size_t)row * HSZ + c0 + 32] = (_Float16)tanhf(a2[r] + P.b_cin[c0 + 32]);
      P.CIN[(size_t)row * HSZ + c0 + 48] = (_Float16)tanhf(a3[r] + P.b_cin[c0 + 48]);
    }
  }
}

__global__ __launch_bounds__(256) void init_kernel(P_t P) {
  int idx = blockIdx.x * 256 + threadIdx.x;
  if (idx < BSZ * HSZ) {
    int row = idx >> 9, i = idx & 511;
    P.CF32[idx] = 0.f; P.HF32[idx] = 0.f; P.HF16[idx] = (_Float16)0.f;
    P.COM[(size_t)row * HH2 + i] = (_Float16)0.f;
    P.COM[(size_t)row * HH2 + 512 + i] = P.CIN[idx];
  }
  if (idx < BSZ) P.NF32[idx] = 0.f;
  if (idx < NCTR) P.CTR[idx] = 0u;
}

// ---------------- main persistent dataflow kernel ----------------
__global__ __launch_bounds__(NTHR) void rnn_main(P_t P) {
  __shared__ __align__(16) _Float16 sm[SM_F16];
  __shared__ f4 red[8][64];     // K-split partial accumulators
  __shared__ float sred[8];
  const int tid = threadIdx.x;
  const int b = blockIdx.x;
  const int lane = tid & 63;
  const int wv = tid >> 6;          // 0..15
  const int ml = lane & 15, q = lane >> 4;
  const int sub = b & 15;

  unsigned* CTA = P.CTR;            // z1 ready   (4 arrivals/sub/step)
  unsigned* CTB = P.CTR + CBAR;     // z2 ready
  unsigned* CTC = P.CTR + 2*CBAR;   // PART ready
  unsigned* CTD = P.CTR + 3*CBAR;   // gx/gh ready
  unsigned* CTE = P.CTR + 4*CBAR;   // state updated

  // ---- stage this block's weight slice into LDS, fragment-major ----
  if (b < 192) {
    const _Float16* W = (b < 64) ? P.WT1 : (b < 128) ? P.WT2 : P.WT3;
    const int j16 = b & 63;
#pragma unroll
    for (int rep = 0; rep < 2; ++rep) {
      int idx = tid + rep * 1024;      // 0..2047 chunks of 8
      int kk = idx >> 6, ln = idx & 63;
      int mlw = ln & 15, qw = ln >> 4;
      *(h8*)(sm + idx * 8) =
          *(const h8*)(W + (size_t)(16 * j16 + mlw) * HH2 + kk * 32 + qw * 8);
    }
  } else {
    const int i = b - 192;
#pragma unroll
    for (int s = 0; s < 3; ++s) {
      int g = 3 * i + s;
      const _Float16* src = (g < 96) ? (P.WTih + (size_t)(16 * g) * HSZ)
                                     : (P.WThh + (size_t)(16 * (g - 96)) * HSZ);
      int idx = tid;                   // 1024 chunks of 8 per tile
      int kk = idx >> 6, ln = idx & 63;
      int mlw = ln & 15, qw = ln >> 4;
      *(h8*)(sm + s * 8192 + idx * 8) =
          *(const h8*)(src + (size_t)mlw * HSZ + kk * 32 + qw * 8);
    }
  }
  __syncthreads();

  if (b < 192) {
    // ---- W-roles: K=1024 GEMM split into two 512-halves across wave pairs ----
    const int role = (b < 64) ? 0 : (b < 128) ? 1 : 2;
    const int cb = (role == 0) ? b : (role == 1) ? b - 64 : b - 128;
    const int colb = 16 * cb + ml;
    const float bia = (role == 0) ? P.b1[colb] : (role == 1) ? P.b2[colb] : P.b3[colb];
    const float w4v = (role == 2) ? P.w4[colb] : 0.f;
    const _Float16* Asrc = (role == 0) ? P.COM : (role == 1) ? P.Z1 : P.Z2;
    unsigned* dep = (role == 0) ? CTE : (role == 1) ? CTA : CTB;
    unsigned* out = (role == 0) ? CTA : (role == 1) ? CTB : CTC;
    const int r = wv & 7, half = wv >> 3, k0 = half * 512;

    for (int t = 0; t < SLEN; ++t) {
      blk_wait16(dep, 4u * (unsigned)(t + (role == 0 ? 0 : 1)));
      f4 a = gemm_frag<512>(Asrc, HH2, k0, sm, r * 16, ml, q, lane);
      if (wv >= 8) red[r][lane] = a;
      __syncthreads();
      if (wv < 8) {
        f4 o = red[r][lane];
        if (role < 2) {
          _Float16* dst = (role == 0) ? P.Z1 : P.Z2;
#pragma unroll
          for (int j = 0; j < 4; ++j)
            dst[(size_t)(r * 16 + q * 4 + j) * HH2 + colb] =
                (_Float16)fmaxf(a[j] + o[j] + bia, 0.f);
        } else {
#pragma unroll
          for (int j = 0; j < 4; ++j) {
            float v = fmaxf(a[j] + o[j] + bia, 0.f) * w4v;
            v += __shfl_xor(v, 1); v += __shfl_xor(v, 2);
            v += __shfl_xor(v, 4); v += __shfl_xor(v, 8);
            if (ml == 0) P.PART[(size_t)cb * BSZ + r * 16 + q * 4 + j] = v;
          }
        }
      }
      blk_arrive16(out, sub);
    }
  } else {
    // ---- gate role: gx/gh GEMMs (dual-B), then alpha + state for rows 2i,2i+1 ----
    const int i = b - 192;
    const _Float16* Asrc = (i < 32) ? P.COM : P.HF16;
    const int alda = (i < 32) ? HH2 : HSZ;
    const float* bsrc = (i < 32) ? P.b_ih : P.b_hh;
    float* gdst = (i < 32) ? P.GX : P.GH;
    const int i0 = (i < 32) ? 3 * i : 3 * (i - 32);
    const int c0 = 16 * i0 + ml, c1 = 16 * (i0 + 1) + ml, c2 = 16 * (i0 + 2) + ml;
    const float bi0 = bsrc[c0], bi1 = bsrc[c1], bi2 = bsrc[c2];

    for (int t = 0; t < SLEN; ++t) {
      blk_wait16(CTE, 4u * (unsigned)t);
      if (wv < 8) {
        f4 a0, a1;
        gemm_frag2<512>(Asrc, alda, sm, sm + 8192, wv * 16, ml, q, lane, a0, a1);
#pragma unroll
        for (int j = 0; j < 4; ++j) {
          size_t rw = (size_t)(wv * 16 + q * 4 + j) * GG3;
          gdst[rw + c0] = a0[j] + bi0;
          gdst[rw + c1] = a1[j] + bi1;
        }
      } else {
        int r = wv - 8;
        f4 a2 = gemm_frag<512>(Asrc, alda, 0, sm + 2 * 8192, r * 16, ml, q, lane);
#pragma unroll
        for (int j = 0; j < 4; ++j)
          gdst[(size_t)(r * 16 + q * 4 + j) * GG3 + c2] = a2[j] + bi2;
      }
      blk_arrive16(CTD, sub);
      blk_wait16(CTC, 4u * (unsigned)(t + 1));
      blk_wait16(CTD, 4u * (unsigned)(t + 1));
      // alpha for rows 2i, 2i+1
      if (wv < 2) {
        int row = 2 * i + wv;
        float v = P.PART[(size_t)lane * BSZ + row];
#pragma unroll
        for (int off = 32; off > 0; off >>= 1) v += __shfl_xor(v, off);
        if (lane == 0) {
          float lg = (v + P.b4[0] + P.LOGI[t * BSZ + row]) * 10.0f;
          float alpha = 1.f / (1.f + expf(-lg));
          float om = 1.f - alpha;
          float n_old = P.NF32[row];
          float nnew = n_old * om + 1.f;
          P.NF32[row] = nnew;
          sred[wv * 4 + 0] = alpha; sred[wv * 4 + 1] = om;
          sred[wv * 4 + 2] = n_old * om; sred[wv * 4 + 3] = nnew;
        }
      }
      __syncthreads();
      {
        int row = 2 * i + (tid >> 9);
        int col = tid & 511;
        int s4 = (tid >> 9) * 4;
        float alpha = sred[s4], om = sred[s4 + 1], nom = sred[s4 + 2], nnew = sred[s4 + 3];
        size_t go = (size_t)row * GG3 + col;
        float xr = P.GX[go], xz = P.GX[go + 512], xn = P.GX[go + 1024];
        float hr = P.GH[go], hz = P.GH[go + 512], hn = P.GH[go + 1024];
        float rgate = 1.f / (1.f + expf(-(xr + hr)));
        float zgate = 1.f / (1.f + expf(-(xz + hz)));
        float ngate = tanhf(xn + rgate * hn);
        size_t ho = (size_t)row * HSZ + col;
        float h_old = P.HF32[ho];
        float hg = (1.f - zgate) * ngate + zgate * h_old;
        float hnew = h_old * om + alpha * hg;
        P.HF32[ho] = hnew; P.HF16[ho] = (_Float16)hnew;
        float c_old = P.CF32[ho];
        float cin_t = (float)P.CIN[((size_t)t * BSZ + row) * HSZ + col];
        float cnew = (c_old * nom + cin_t) / nnew;
        P.CF32[ho] = cnew;
        P.COM[(size_t)row * HH2 + col] = (_Float16)cnew;
        if (t + 1 < SLEN)
          P.COM[(size_t)row * HH2 + 512 + col] =
              P.CIN[((size_t)(t + 1) * BSZ + row) * HSZ + col];
      }
      blk_arrive16(CTE, sub);
    }

    // ---- tail (gate blocks only): final GRU + output ----
    blk_wait16(CTE, 4u * (unsigned)SLEN);
    if (wv < 8) {
      f4 a0, a1;
      gemm_frag2<512>(Asrc, alda, sm, sm + 8192, wv * 16, ml, q, lane, a0, a1);
#pragma unroll
      for (int j = 0; j < 4; ++j) {
        size_t rw = (size_t)(wv * 16 + q * 4 + j) * GG3;
        gdst[rw + c0] = a0[j] + bi0;
        gdst[rw + c1] = a1[j] + bi1;
      }
    } else {
      int r = wv - 8;
      f4 a2 = gemm_frag<512>(Asrc, alda, 0, sm + 2 * 8192, r * 16, ml, q, lane);
#pragma unroll
      for (int j = 0; j < 4; ++j)
        gdst[(size_t)(r * 16 + q * 4 + j) * GG3 + c2] = a2[j] + bi2;
    }
    blk_arrive16(CTD, sub);
    blk_wait16(CTD, 4u * (unsigned)(SLEN + 1));
    __syncthreads();  // LDS weights no longer needed; reuse sm as float hfin[1024]
    {
      float* hf = (float*)sm;
      int row = 2 * i + (tid >> 9);
      int col = tid & 511;
      size_t go = (size_t)row * GG3 + col;
      float xr = P.GX[go], xz = P.GX[go + 512], xn = P.GX[go + 1024];
      float hr = P.GH[go], hz = P.GH[go + 512], hn = P.GH[go + 1024];
      float rgate = 1.f / (1.f + expf(-(xr + hr)));
      float zgate = 1.f / (1.f + expf(-(xz + hz)));
      float ngate = tanhf(xn + rgate * hn);
      float h_old = P.HF32[(size_t)row * HSZ + col];
      hf[tid] = (1.f - zgate) * ngate + zgate * h_old;
    }
    __syncthreads();
    if (wv < 2) {
      const float* hf = (const float*)sm;
      int row = 2 * i + wv;
      float accs[OSZ];
#pragma unroll
      for (int c = 0; c < OSZ; ++c) accs[c] = 0.f;
#pragma unroll
      for (int j = 0; j < 8; ++j) {
        float hv = hf[wv * 512 + lane * 8 + j];
        const float* wr = P.w_out + (size_t)(lane * 8 + j) * OSZ;
#pragma unroll
        for (int c = 0; c < OSZ; ++c) accs[c] += hv * wr[c];
      }
#pragma unroll
      for (int c = 0; c < OSZ; ++c) {
        float v = accs[c];
#pragma unroll
        for (int off = 32; off > 0; off >>= 1) v += __shfl_xor(v, off);
        if (lane == 0) P.out[row * OSZ + c] = v + P.b_out[c];
      }
    }
  }
}

// ---------------- host ----------------
extern "C" void kernel_launch(void* const* d_in, const int* in_sizes, int n_in,
                              void* d_out, int out_size, void* d_ws, size_t ws_size,
                              hipStream_t stream) {
  const float* x     = (const float*)d_in[0];
  const float* noise = (const float*)d_in[1];
  const float* w_cin = (const float*)d_in[2];
  const float* b_cin = (const float*)d_in[3];
  const float* w1    = (const float*)d_in[4];
  const float* b1    = (const float*)d_in[5];
  const float* w2    = (const float*)d_in[6];
  const float* b2    = (const float*)d_in[7];
  const float* w3    = (const float*)d_in[8];
  const float* b3    = (const float*)d_in[9];
  const float* w4    = (const float*)d_in[10];
  const float* b4    = (const float*)d_in[11];
  const float* w_ih  = (const float*)d_in[12];
  const float* b_ih  = (const float*)d_in[13];
  const float* w_hh  = (const float*)d_in[14];
  const float* b_hh  = (const float*)d_in[15];
  const float* w_out = (const float*)d_in[16];
  const float* b_out = (const float*)d_in[17];

  char* ws = (char*)d_ws;
  size_t off = 0;
  auto alloc = [&](size_t bytes) -> void* {
    void* p = ws + off;
    off = (off + bytes + 255) & ~(size_t)255;
    return p;
  };

  P_t P;
  P.x = x; P.noise = noise; P.b_cin = b_cin; P.b1 = b1; P.b2 = b2; P.b3 = b3;
  P.w4 = w4; P.b4 = b4; P.b_ih = b_ih; P.b_hh = b_hh; P.w_out = w_out; P.b_out = b_out;
  P.WT1   = (_Float16*)alloc((size_t)HH2 * HH2 * 2);
  P.WT2   = (_Float16*)alloc((size_t)HH2 * HH2 * 2);
  P.WT3   = (_Float16*)alloc((size_t)HH2 * HH2 * 2);
  P.WTih  = (_Float16*)alloc((size_t)GG3 * HSZ * 2);
  P.WThh  = (_Float16*)alloc((size_t)GG3 * HSZ * 2);
  P.WTcin = (_Float16*)alloc((size_t)HSZ * DIN * 2);
  P.CIN   = (_Float16*)alloc((size_t)SLEN * BSZ * HSZ * 2);
  P.COM   = (_Float16*)alloc((size_t)BSZ * HH2 * 2);
  P.Z1    = (_Float16*)alloc((size_t)BSZ * HH2 * 2);
  P.Z2    = (_Float16*)alloc((size_t)BSZ * HH2 * 2);
  P.HF16  = (_Float16*)alloc((size_t)BSZ * HSZ * 2);
  P.LOGI  = (float*)alloc((size_t)SLEN * BSZ * 4);
  P.GX    = (float*)alloc((size_t)BSZ * GG3 * 4);
  P.GH    = (float*)alloc((size_t)BSZ * GG3 * 4);
  P.PART  = (float*)alloc((size_t)64 * BSZ * 4);
  P.HF32  = (float*)alloc((size_t)BSZ * HSZ * 4);
  P.CF32  = (float*)alloc((size_t)BSZ * HSZ * 4);
  P.NF32  = (float*)alloc((size_t)BSZ * 4);
  P.CTR   = (unsigned*)alloc(NCTR * 4);
  P.out   = (float*)d_out;

  transpose_cvt<<<(HH2 / 32) * (HH2 / 32), 256, 0, stream>>>(w1, P.WT1, HH2, HH2);
  transpose_cvt<<<(HH2 / 32) * (HH2 / 32), 256, 0, stream>>>(w2, P.WT2, HH2, HH2);
  transpose_cvt<<<(HH2 / 32) * (HH2 / 32), 256, 0, stream>>>(w3, P.WT3, HH2, HH2);
  transpose_cvt<<<(GG3 / 32) * (HSZ / 32), 256, 0, stream>>>(w_ih, P.WTih, HSZ, GG3);
  transpose_cvt<<<(GG3 / 32) * (HSZ / 32), 256, 0, stream>>>(w_hh, P.WThh, HSZ, GG3);
  transpose_cvt<<<(HSZ / 32) * (DIN / 32), 256, 0, stream>>>(w_cin, P.WTcin, DIN, HSZ);

  cin_kernel<<<1024, 256, 0, stream>>>(P);
  init_kernel<<<256, 256, 0, stream>>>(P);
  rnn_main<<<NBLK, NTHR, 0, stream>>>(P);
}

// Round 8
// 8619.005 us; speedup vs baseline: 3.3550x; 1.2846x over previous
//
#include <hip/hip_runtime.h>
#include <math.h>

// Problem dims
#define SLEN 256
#define BSZ  128
#define DIN  128
#define HSZ  512
#define HH2  1024
#define GG3  1536
#define OSZ  25

typedef _Float16 h8 __attribute__((ext_vector_type(8)));
typedef float    f4 __attribute__((ext_vector_type(4)));

// Dataflow-pipeline geometry: 256 blocks x 1024 threads (16 waves), 1 block/CU.
// Roles: b<64: W1 | b<128: W2 | b<192: W3(+PART) | b<256: gates(+state)
#define NBLK 256
#define NTHR 1024

// LDS (f16), fragment-major B layout [K/32][64 lanes][8]:
//   W-tile 16x1024 -> 16384 f16 (32 KB); 3 gate tiles 16x512 -> 24576 f16 (48 KB)
#define SM_F16 24576

// Barrier counters: 5 barriers x 16 subs x 32-dword stride (128B lines)
#define CSUB 32
#define CBAR (16 * CSUB)
#define NCTR (5 * CBAR)

struct P_t {
  const float *x, *noise, *b_cin, *b1, *b2, *b3, *w4, *b4, *b_ih, *b_hh, *w_out, *b_out;
  _Float16 *WT1, *WT2, *WT3, *WTih, *WThh, *WTcin;  // f16 transposed [N][K]
  _Float16 *CIN, *COMlo, *Z1, *Z2, *HF16;
  float *LOGI, *GX, *GH, *PART, *HF32, *CF32, *NF32;
  unsigned *CTR;
  float *out;
};

// ---------------- LIC-coherent (sc0 sc1) load/store primitives ----------------
// Loads bypass L1+L2 and are served from the device-coherent LIC; stores land in
// LIC (write-through/no-allocate).  This removes ALL buffer_wbl2/buffer_inv
// cache walks from the hot loop.
__device__ __forceinline__ void lic_load8(h8* d, const _Float16* p) {
  asm volatile(
      "global_load_dwordx4 %0, %8, off sc0 sc1\n\t"
      "global_load_dwordx4 %1, %8, off offset:64 sc0 sc1\n\t"
      "global_load_dwordx4 %2, %8, off offset:128 sc0 sc1\n\t"
      "global_load_dwordx4 %3, %8, off offset:192 sc0 sc1\n\t"
      "global_load_dwordx4 %4, %8, off offset:256 sc0 sc1\n\t"
      "global_load_dwordx4 %5, %8, off offset:320 sc0 sc1\n\t"
      "global_load_dwordx4 %6, %8, off offset:384 sc0 sc1\n\t"
      "global_load_dwordx4 %7, %8, off offset:448 sc0 sc1\n\t"
      "s_waitcnt vmcnt(0)"
      : "=&v"(d[0]), "=&v"(d[1]), "=&v"(d[2]), "=&v"(d[3]),
        "=&v"(d[4]), "=&v"(d[5]), "=&v"(d[6]), "=&v"(d[7])
      : "v"(p) : "memory");
}
__device__ __forceinline__ float lic_load4(const float* p) {
  float v;
  asm volatile("global_load_dword %0, %1, off sc0 sc1\n\ts_waitcnt vmcnt(0)"
               : "=v"(v) : "v"(p) : "memory");
  return v;
}
// 6 gate values (xr,xz,xn,hr,hz,hn); bases pre-offset by +512 floats.
__device__ __forceinline__ void lic_load_gates(float* o, const float* gxm, const float* ghm) {
  asm volatile(
      "global_load_dword %0, %6, off offset:-2048 sc0 sc1\n\t"
      "global_load_dword %1, %6, off sc0 sc1\n\t"
      "global_load_dword %2, %6, off offset:2048 sc0 sc1\n\t"
      "global_load_dword %3, %7, off offset:-2048 sc0 sc1\n\t"
      "global_load_dword %4, %7, off sc0 sc1\n\t"
      "global_load_dword %5, %7, off offset:2048 sc0 sc1\n\t"
      "s_waitcnt vmcnt(0)"
      : "=&v"(o[0]), "=&v"(o[1]), "=&v"(o[2]),
        "=&v"(o[3]), "=&v"(o[4]), "=&v"(o[5])
      : "v"(gxm), "v"(ghm) : "memory");
}
__device__ __forceinline__ void lic_store2(_Float16* p, _Float16 v) {
  union { _Float16 h; unsigned short s; } u; u.h = v;
  unsigned w = u.s;
  asm volatile("global_store_short %0, %1, off sc0 sc1" :: "v"(p), "v"(w) : "memory");
}
__device__ __forceinline__ void lic_store4(float* p, float v) {
  asm volatile("global_store_dword %0, %1, off sc0 sc1" :: "v"(p), "v"(v) : "memory");
}

// ---------------- split device barrier, fence-free ----------------
// Release ordering: every wave drains its own (sc) stores via vmcnt(0), then the
// block barrier, then one flag atomicAdd (in-order VMEM after barrier).
__device__ __forceinline__ void blk_arrive16(unsigned* base, int sub) {
  asm volatile("s_waitcnt vmcnt(0)" ::: "memory");
  __syncthreads();
  if (threadIdx.x == 0) atomicAdd(base + sub * CSUB, 1u);
}
// Acquire: data reads are explicitly LIC-coherent, so detection alone suffices.
__device__ __forceinline__ void blk_wait16(unsigned* base, unsigned target) {
  if (threadIdx.x < 16) {
    unsigned* p = base + threadIdx.x * CSUB;
    while (__hip_atomic_load(p, __ATOMIC_RELAXED, __HIP_MEMORY_SCOPE_AGENT) < target)
      __builtin_amdgcn_s_sleep(1);
  }
  __syncthreads();
}

// ---------------- MFMA fragment GEMMs ----------------
__device__ __forceinline__ f4 mfma16(h8 a, h8 b, f4 c) {
  return __builtin_amdgcn_mfma_f32_16x16x32_f16(a, b, c, 0, 0, 0);
}
// K=512, A via LIC-coherent loads. ap = &A[(m0+ml)*lda + q*8].
__device__ __forceinline__ f4 gemm_sc512(const _Float16* ap, const _Float16* Bs, int lane) {
  const _Float16* bp = Bs + lane * 8;
  h8 A[8];
  f4 acc = {0.f, 0.f, 0.f, 0.f};
  lic_load8(A, ap);
#pragma unroll
  for (int c = 0; c < 8; ++c) acc = mfma16(A[c], *(const h8*)(bp + c * 512), acc);
  lic_load8(A, ap + 256);
#pragma unroll
  for (int c = 0; c < 8; ++c) acc = mfma16(A[c], *(const h8*)(bp + (c + 8) * 512), acc);
  return acc;
}
// K=512 dual-B (A stream reused).
__device__ __forceinline__ void gemm2_sc512(const _Float16* ap, const _Float16* B0,
                                            const _Float16* B1, int lane, f4& o0, f4& o1) {
  const _Float16* b0 = B0 + lane * 8;
  const _Float16* b1 = B1 + lane * 8;
  h8 A[8];
  f4 x = {0.f, 0.f, 0.f, 0.f}, y = x;
  lic_load8(A, ap);
#pragma unroll
  for (int c = 0; c < 8; ++c) {
    x = mfma16(A[c], *(const h8*)(b0 + c * 512), x);
    y = mfma16(A[c], *(const h8*)(b1 + c * 512), y);
  }
  lic_load8(A, ap + 256);
#pragma unroll
  for (int c = 0; c < 8; ++c) {
    x = mfma16(A[c], *(const h8*)(b0 + (c + 8) * 512), x);
    y = mfma16(A[c], *(const h8*)(b1 + (c + 8) * 512), y);
  }
  o0 = x; o1 = y;
}
// K=512 over immutable data (CIN) — normal cached loads.
__device__ __forceinline__ f4 gemm_cached512(const _Float16* ap, const _Float16* Bs, int lane) {
  const _Float16* bp = Bs + lane * 8;
  f4 acc = {0.f, 0.f, 0.f, 0.f};
#pragma unroll
  for (int c = 0; c < 16; ++c)
    acc = mfma16(*(const h8*)(ap + c * 32), *(const h8*)(bp + c * 512), acc);
  return acc;
}

// ---------------- setup kernels (R2-proven) ----------------
__global__ __launch_bounds__(256) void transpose_cvt(const float* __restrict__ src,
    _Float16* __restrict__ dst, int K, int N) {
  __shared__ float tl[32][33];
  int nt = N >> 5;
  int bx = blockIdx.x % nt, by = blockIdx.x / nt;
  int n0 = bx << 5, k0 = by << 5;
  int tx = threadIdx.x & 31, ty = threadIdx.x >> 5;
#pragma unroll
  for (int i = 0; i < 4; ++i) {
    int r = ty + (i << 3);
    tl[r][tx] = src[(size_t)(k0 + r) * N + n0 + tx];
  }
  __syncthreads();
#pragma unroll
  for (int i = 0; i < 4; ++i) {
    int r = ty + (i << 3);
    dst[(size_t)(n0 + r) * K + k0 + tx] = (_Float16)tl[tx][r];
  }
}

__global__ __launch_bounds__(256) void cin_kernel(P_t P) {
  int tid = blockIdx.x * blockDim.x + threadIdx.x;
  if (tid < SLEN * BSZ) {
    float u = P.noise[tid];
    P.LOGI[tid] = logf(u) - log1pf(-u);
  }
  int gw = tid >> 6, lane = tid & 63;
  int nw = (gridDim.x * blockDim.x) >> 6;
  int ml = lane & 15, q = lane >> 4;
  const int MT = (SLEN * BSZ) / 16;
  for (int tt = gw; tt < MT * 8; tt += nw) {
    int mt = tt & (MT - 1), nt = tt / MT;
    int m0 = mt * 16, n0 = nt * 64;
    int m = m0 + ml, b = m & 127, s = m >> 7;
    const float* ap = P.x + ((size_t)b * SLEN + s) * DIN + q * 8;
    const _Float16* bp = P.WTcin + (size_t)(n0 + ml) * DIN + q * 8;
    f4 a0 = {0,0,0,0}, a1 = a0, a2 = a0, a3 = a0;
#pragma unroll
    for (int k = 0; k < DIN; k += 32) {
      f4 lo = *(const f4*)(ap + k);
      f4 hi = *(const f4*)(ap + k + 4);
      h8 av;
      av[0] = (_Float16)lo[0]; av[1] = (_Float16)lo[1];
      av[2] = (_Float16)lo[2]; av[3] = (_Float16)lo[3];
      av[4] = (_Float16)hi[0]; av[5] = (_Float16)hi[1];
      av[6] = (_Float16)hi[2]; av[7] = (_Float16)hi[3];
      a0 = __builtin_amdgcn_mfma_f32_16x16x32_f16(av, *(const h8*)(bp + k),          a0, 0,0,0);
      a1 = __builtin_amdgcn_mfma_f32_16x16x32_f16(av, *(const h8*)(bp + 16*DIN + k), a1, 0,0,0);
      a2 = __builtin_amdgcn_mfma_f32_16x16x32_f16(av, *(const h8*)(bp + 32*DIN + k), a2, 0,0,0);
      a3 = __builtin_amdgcn_mfma_f32_16x16x32_f16(av, *(const h8*)(bp + 48*DIN + k), a3, 0,0,0);
    }
#pragma unroll
    for (int r = 0; r < 4; ++r) {
      int row = m0 + q * 4 + r;
      int c0 = n0 + ml;
      P.CIN[(size_t)row * HSZ + c0     ] = (_Float16)tanhf(a0[r] + P.b_cin[c0]);
      P.CIN[(size_t)row * HSZ + c0 + 16] = (_Float16)tanhf(a1[r] + P.b_cin[c0 + 16]);
      P.CIN[(size_t)row * HSZ + c0 + 32] = (_Float16)tanhf(a2[r] + P.b_cin[c0 + 32]);
      P.CIN[(size_t)row * HSZ + c0 + 48] = (_Float16)tanhf(a3[r] + P.b_cin[c0 + 48]);
    }
  }
}

__global__ __launch_bounds__(256) void init_kernel(P_t P) {
  int idx = blockIdx.x * 256 + threadIdx.x;
  if (idx < BSZ * HSZ) {
    P.CF32[idx] = 0.f; P.HF32[idx] = 0.f;
    P.HF16[idx] = (_Float16)0.f; P.COMlo[idx] = (_Float16)0.f;
  }
  if (idx < BSZ) P.NF32[idx] = 0.f;
  if (idx < NCTR) P.CTR[idx] = 0u;
}

// ---------------- main persistent dataflow kernel ----------------
__global__ __launch_bounds__(NTHR) void rnn_main(P_t P) {
  __shared__ __align__(16) _Float16 sm[SM_F16];
  __shared__ f4 red[8][64];
  __shared__ float sred[8];
  const int tid = threadIdx.x;
  const int b = blockIdx.x;
  const int lane = tid & 63;
  const int wv = tid >> 6;          // 0..15
  const int ml = lane & 15, q = lane >> 4;
  const int sub = b & 15;

  unsigned* CTA = P.CTR;            // z1 ready
  unsigned* CTB = P.CTR + CBAR;     // z2 ready
  unsigned* CTC = P.CTR + 2*CBAR;   // PART ready
  unsigned* CTD = P.CTR + 3*CBAR;   // gx/gh ready
  unsigned* CTE = P.CTR + 4*CBAR;   // state updated

  // ---- stage this block's weight slice into LDS, fragment-major ----
  if (b < 192) {
    const _Float16* W = (b < 64) ? P.WT1 : (b < 128) ? P.WT2 : P.WT3;
    const int j16 = b & 63;
#pragma unroll
    for (int rep = 0; rep < 2; ++rep) {
      int idx = tid + rep * 1024;      // 0..2047 chunks of 8
      int kk = idx >> 6, ln = idx & 63;
      int mlw = ln & 15, qw = ln >> 4;
      *(h8*)(sm + idx * 8) =
          *(const h8*)(W + (size_t)(16 * j16 + mlw) * HH2 + kk * 32 + qw * 8);
    }
  } else {
    const int i = b - 192;
#pragma unroll
    for (int s = 0; s < 3; ++s) {
      int g = 3 * i + s;
      const _Float16* src = (g < 96) ? (P.WTih + (size_t)(16 * g) * HSZ)
                                     : (P.WThh + (size_t)(16 * (g - 96)) * HSZ);
      int idx = tid;                   // 1024 chunks of 8 per tile
      int kk = idx >> 6, ln = idx & 63;
      int mlw = ln & 15, qw = ln >> 4;
      *(h8*)(sm + s * 8192 + idx * 8) =
          *(const h8*)(src + (size_t)mlw * HSZ + kk * 32 + qw * 8);
    }
  }
  __syncthreads();

  if (b < 192) {
    // ---- W-roles: K=1024 split into two 512-halves across wave pairs ----
    const int role = (b < 64) ? 0 : (b < 128) ? 1 : 2;
    const int cb = (role == 0) ? b : (role == 1) ? b - 64 : b - 128;
    const int colb = 16 * cb + ml;
    const float bia = (role == 0) ? P.b1[colb] : (role == 1) ? P.b2[colb] : P.b3[colb];
    const float w4v = (role == 2) ? P.w4[colb] : 0.f;
    unsigned* dep = (role == 0) ? CTE : (role == 1) ? CTA : CTB;
    unsigned* out = (role == 0) ? CTA : (role == 1) ? CTB : CTC;
    const int r = wv & 7, half = wv >> 3, m0 = r * 16;

    for (int t = 0; t < SLEN; ++t) {
      blk_wait16(dep, 4u * (unsigned)(t + (role == 0 ? 0 : 1)));
      f4 a;
      if (role == 0) {
        if (half == 0)
          a = gemm_sc512(P.COMlo + (size_t)(m0 + ml) * HSZ + q * 8, sm, lane);
        else
          a = gemm_cached512(P.CIN + ((size_t)t * BSZ + m0 + ml) * HSZ + q * 8,
                             sm + 16 * 512, lane);
      } else {
        const _Float16* A = (role == 1) ? P.Z1 : P.Z2;
        a = gemm_sc512(A + (size_t)(m0 + ml) * HH2 + half * 512 + q * 8,
                       sm + half * 16 * 512, lane);
      }
      if (wv >= 8) red[r][lane] = a;
      __syncthreads();
      if (wv < 8) {
        f4 o = red[r][lane];
        if (role < 2) {
          _Float16* dst = (role == 0) ? P.Z1 : P.Z2;
#pragma unroll
          for (int j = 0; j < 4; ++j)
            lic_store2(dst + (size_t)(m0 + q * 4 + j) * HH2 + colb,
                       (_Float16)fmaxf(a[j] + o[j] + bia, 0.f));
        } else {
#pragma unroll
          for (int j = 0; j < 4; ++j) {
            float v = fmaxf(a[j] + o[j] + bia, 0.f) * w4v;
            v += __shfl_xor(v, 1); v += __shfl_xor(v, 2);
            v += __shfl_xor(v, 4); v += __shfl_xor(v, 8);
            if (ml == 0) lic_store4(P.PART + (size_t)cb * BSZ + m0 + q * 4 + j, v);
          }
        }
      }
      blk_arrive16(out, sub);
    }
  } else {
    // ---- gate role: gx/gh GEMMs, then alpha + state for rows 2i,2i+1 ----
    const int i = b - 192;
    const bool isgx = (i < 32);
    const _Float16* Ag = isgx ? P.COMlo : P.HF16;
    const float* bsrc = isgx ? P.b_ih : P.b_hh;
    float* gdst = isgx ? P.GX : P.GH;
    const int i0 = isgx ? 3 * i : 3 * (i - 32);
    const int c0 = 16 * i0 + ml, c1 = 16 * (i0 + 1) + ml, c2 = 16 * (i0 + 2) + ml;
    const float bi0 = bsrc[c0], bi1 = bsrc[c1], bi2 = bsrc[c2];

    for (int t = 0; t < SLEN; ++t) {
      blk_wait16(CTE, 4u * (unsigned)t);
      if (wv < 8) {
        const int m0 = wv * 16;
        f4 a0, a1;
        gemm2_sc512(Ag + (size_t)(m0 + ml) * HSZ + q * 8, sm, sm + 8192, lane, a0, a1);
#pragma unroll
        for (int j = 0; j < 4; ++j) {
          size_t rw = (size_t)(m0 + q * 4 + j) * GG3;
          lic_store4(gdst + rw + c0, a0[j] + bi0);
          lic_store4(gdst + rw + c1, a1[j] + bi1);
        }
      } else {
        const int m0 = (wv - 8) * 16;
        f4 a2 = gemm_sc512(Ag + (size_t)(m0 + ml) * HSZ + q * 8, sm + 2 * 8192, lane);
#pragma unroll
        for (int j = 0; j < 4; ++j)
          lic_store4(gdst + (size_t)(m0 + q * 4 + j) * GG3 + c2, a2[j] + bi2);
      }
      blk_arrive16(CTD, sub);
      blk_wait16(CTC, 4u * (unsigned)(t + 1));
      blk_wait16(CTD, 4u * (unsigned)(t + 1));
      // alpha for rows 2i, 2i+1
      if (wv < 2) {
        int row = 2 * i + wv;
        float v = lic_load4(P.PART + (size_t)lane * BSZ + row);
#pragma unroll
        for (int off = 32; off > 0; off >>= 1) v += __shfl_xor(v, off);
        if (lane == 0) {
          float lg = (v + P.b4[0] + P.LOGI[t * BSZ + row]) * 10.0f;
          float alpha = 1.f / (1.f + expf(-lg));
          float om = 1.f - alpha;
          float n_old = P.NF32[row];
          float nnew = n_old * om + 1.f;
          P.NF32[row] = nnew;
          sred[wv * 4 + 0] = alpha; sred[wv * 4 + 1] = om;
          sred[wv * 4 + 2] = n_old * om; sred[wv * 4 + 3] = nnew;
        }
      }
      __syncthreads();
      {
        int rr = tid >> 9, col = tid & 511, row = 2 * i + rr;
        int s4 = rr * 4;
        float alpha = sred[s4], om = sred[s4 + 1], nom = sred[s4 + 2], nnew = sred[s4 + 3];
        float g[6];
        lic_load_gates(g, P.GX + (size_t)row * GG3 + col + 512,
                          P.GH + (size_t)row * GG3 + col + 512);
        float rgate = 1.f / (1.f + expf(-(g[0] + g[3])));
        float zgate = 1.f / (1.f + expf(-(g[1] + g[4])));
        float ngate = tanhf(g[2] + rgate * g[5]);
        size_t ho = (size_t)row * HSZ + col;
        float h_old = P.HF32[ho];
        float hg = (1.f - zgate) * ngate + zgate * h_old;
        float hnew = h_old * om + alpha * hg;
        P.HF32[ho] = hnew;
        lic_store2(P.HF16 + ho, (_Float16)hnew);
        float c_old = P.CF32[ho];
        float cin_t = (float)P.CIN[((size_t)t * BSZ + row) * HSZ + col];
        float cnew = (c_old * nom + cin_t) / nnew;
        P.CF32[ho] = cnew;
        lic_store2(P.COMlo + ho, (_Float16)cnew);
      }
      blk_arrive16(CTE, sub);
    }

    // ---- tail (gate blocks only): final GRU + output ----
    blk_wait16(CTE, 4u * (unsigned)SLEN);
    if (wv < 8) {
      const int m0 = wv * 16;
      f4 a0, a1;
      gemm2_sc512(Ag + (size_t)(m0 + ml) * HSZ + q * 8, sm, sm + 8192, lane, a0, a1);
#pragma unroll
      for (int j = 0; j < 4; ++j) {
        size_t rw = (size_t)(m0 + q * 4 + j) * GG3;
        lic_store4(gdst + rw + c0, a0[j] + bi0);
        lic_store4(gdst + rw + c1, a1[j] + bi1);
      }
    } else {
      const int m0 = (wv - 8) * 16;
      f4 a2 = gemm_sc512(Ag + (size_t)(m0 + ml) * HSZ + q * 8, sm + 2 * 8192, lane);
#pragma unroll
      for (int j = 0; j < 4; ++j)
        lic_store4(gdst + (size_t)(m0 + q * 4 + j) * GG3 + c2, a2[j] + bi2);
    }
    blk_arrive16(CTD, sub);
    blk_wait16(CTD, 4u * (unsigned)(SLEN + 1));
    __syncthreads();  // weights done; reuse sm as float hfin[1024]
    {
      float* hf = (float*)sm;
      int rr = tid >> 9, col = tid & 511, row = 2 * i + rr;
      float g[6];
      lic_load_gates(g, P.GX + (size_t)row * GG3 + col + 512,
                        P.GH + (size_t)row * GG3 + col + 512);
      float rgate = 1.f / (1.f + expf(-(g[0] + g[3])));
      float zgate = 1.f / (1.f + expf(-(g[1] + g[4])));
      float ngate = tanhf(g[2] + rgate * g[5]);
      float h_old = P.HF32[(size_t)row * HSZ + col];
      hf[tid] = (1.f - zgate) * ngate + zgate * h_old;
    }
    __syncthreads();
    if (wv < 2) {
      const float* hf = (const float*)sm;
      int row = 2 * i + wv;
      float accs[OSZ];
#pragma unroll
      for (int c = 0; c < OSZ; ++c) accs[c] = 0.f;
#pragma unroll
      for (int j = 0; j < 8; ++j) {
        float hv = hf[wv * 512 + lane * 8 + j];
        const float* wr = P.w_out + (size_t)(lane * 8 + j) * OSZ;
#pragma unroll
        for (int c = 0; c < OSZ; ++c) accs[c] += hv * wr[c];
      }
#pragma unroll
      for (int c = 0; c < OSZ; ++c) {
        float v = accs[c];
#pragma unroll
        for (int off = 32; off > 0; off >>= 1) v += __shfl_xor(v, off);
        if (lane == 0) P.out[row * OSZ + c] = v + P.b_out[c];
      }
    }
  }
}

// ---------------- host ----------------
extern "C" void kernel_launch(void* const* d_in, const int* in_sizes, int n_in,
                              void* d_out, int out_size, void* d_ws, size_t ws_size,
                              hipStream_t stream) {
  const float* x     = (const float*)d_in[0];
  const float* noise = (const float*)d_in[1];
  const float* w_cin = (const float*)d_in[2];
  const float* b_cin = (const float*)d_in[3];
  const float* w1    = (const float*)d_in[4];
  const float* b1    = (const float*)d_in[5];
  const float* w2    = (const float*)d_in[6];
  const float* b2    = (const float*)d_in[7];
  const float* w3    = (const float*)d_in[8];
  const float* b3    = (const float*)d_in[9];
  const float* w4    = (const float*)d_in[10];
  const float* b4    = (const float*)d_in[11];
  const float* w_ih  = (const float*)d_in[12];
  const float* b_ih  = (const float*)d_in[13];
  const float* w_hh  = (const float*)d_in[14];
  const float* b_hh  = (const float*)d_in[15];
  const float* w_out = (const float*)d_in[16];
  const float* b_out = (const float*)d_in[17];

  char* ws = (char*)d_ws;
  size_t off = 0;
  auto alloc = [&](size_t bytes) -> void* {
    void* p = ws + off;
    off = (off + bytes + 255) & ~(size_t)255;
    return p;
  };

  P_t P;
  P.x = x; P.noise = noise; P.b_cin = b_cin; P.b1 = b1; P.b2 = b2; P.b3 = b3;
  P.w4 = w4; P.b4 = b4; P.b_ih = b_ih; P.b_hh = b_hh; P.w_out = w_out; P.b_out = b_out;
  P.WT1   = (_Float16*)alloc((size_t)HH2 * HH2 * 2);
  P.WT2   = (_Float16*)alloc((size_t)HH2 * HH2 * 2);
  P.WT3   = (_Float16*)alloc((size_t)HH2 * HH2 * 2);
  P.WTih  = (_Float16*)alloc((size_t)GG3 * HSZ * 2);
  P.WThh  = (_Float16*)alloc((size_t)GG3 * HSZ * 2);
  P.WTcin = (_Float16*)alloc((size_t)HSZ * DIN * 2);
  P.CIN   = (_Float16*)alloc((size_t)SLEN * BSZ * HSZ * 2);
  P.COMlo = (_Float16*)alloc((size_t)BSZ * HSZ * 2);
  P.Z1    = (_Float16*)alloc((size_t)BSZ * HH2 * 2);
  P.Z2    = (_Float16*)alloc((size_t)BSZ * HH2 * 2);
  P.HF16  = (_Float16*)alloc((size_t)BSZ * HSZ * 2);
  P.LOGI  = (float*)alloc((size_t)SLEN * BSZ * 4);
  P.GX    = (float*)alloc((size_t)BSZ * GG3 * 4);
  P.GH    = (float*)alloc((size_t)BSZ * GG3 * 4);
  P.PART  = (float*)alloc((size_t)64 * BSZ * 4);
  P.HF32  = (float*)alloc((size_t)BSZ * HSZ * 4);
  P.CF32  = (float*)alloc((size_t)BSZ * HSZ * 4);
  P.NF32  = (float*)alloc((size_t)BSZ * 4);
  P.CTR   = (unsigned*)alloc(NCTR * 4);
  P.out   = (float*)d_out;

  transpose_cvt<<<(HH2 / 32) * (HH2 / 32), 256, 0, stream>>>(w1, P.WT1, HH2, HH2);
  transpose_cvt<<<(HH2 / 32) * (HH2 / 32), 256, 0, stream>>>(w2, P.WT2, HH2, HH2);
  transpose_cvt<<<(HH2 / 32) * (HH2 / 32), 256, 0, stream>>>(w3, P.WT3, HH2, HH2);
  transpose_cvt<<<(GG3 / 32) * (HSZ / 32), 256, 0, stream>>>(w_ih, P.WTih, HSZ, GG3);
  transpose_cvt<<<(GG3 / 32) * (HSZ / 32), 256, 0, stream>>>(w_hh, P.WThh, HSZ, GG3);
  transpose_cvt<<<(HSZ / 32) * (DIN / 32), 256, 0, stream>>>(w_cin, P.WTcin, DIN, HSZ);

  cin_kernel<<<1024, 256, 0, stream>>>(P);
  init_kernel<<<256, 256, 0, stream>>>(P);
  rnn_main<<<NBLK, NTHR, 0, stream>>>(P);
}